// Round 11
// baseline (391.270 us; speedup 1.0000x reference)
//
#include <hip/hip_runtime.h>
#include <hip/hip_bf16.h>

#define NODES 50000
#define NEDGE 800000
#define ETOT  850000   /* NEDGE + NODES self loops */

#define NRANGE 49            /* ceil(NODES/1024) dst ranges */
#define SB 256               /* scatter/hist blocks */
#define ES ((ETOT + SB - 1) / SB)   /* 3321 edges per slice */

#define XF_TILES 1563        /* ceil(NODES/32) */
#define HIST_BLKS 256
#define FUSE_GRID (2 * HIST_BLKS + (XF_TILES - HIST_BLKS))  /* 1819 */

typedef __hip_bfloat16 bf16;
typedef __attribute__((ext_vector_type(8))) short bf16x8;
typedef __attribute__((ext_vector_type(4))) float f32x4;

__device__ __forceinline__ bf16 f2bf(float v) { return __float2bfloat16(v); }
__device__ __forceinline__ float bflo(unsigned int v) { return __uint_as_float(v << 16); }
__device__ __forceinline__ float bfhi(unsigned int v) { return __uint_as_float(v & 0xffff0000u); }

__device__ __forceinline__ unsigned int pack2(float a, float b) {
    bf16 x = f2bf(a), y = f2bf(b);
    unsigned short xs = *reinterpret_cast<unsigned short*>(&x);
    unsigned short ys = *reinterpret_cast<unsigned short*>(&y);
    return ((unsigned int)ys << 16) | (unsigned int)xs;
}

__device__ __forceinline__ unsigned short bfbits(float v) {
    bf16 x = f2bf(v);
    return *reinterpret_cast<unsigned short*>(&x);
}

// Dekker split: hi = bf16(v), lo = bf16(v - float(hi))
__device__ __forceinline__ void hilo(float v, unsigned short& h, unsigned short& l) {
    h = bfbits(v);
    float hv = __uint_as_float((unsigned int)h << 16);
    l = bfbits(v - hv);
}

// split 8 fp32 -> hi/lo bf16x8
__device__ __forceinline__ void split8(const float* v, bf16x8& hi, bf16x8& lo) {
    #pragma unroll
    for (int e = 0; e < 8; ++e) {
        unsigned short hb, lb;
        hilo(v[e], hb, lb);
        ((short*)&hi)[e] = (short)hb;
        ((short*)&lo)[e] = (short)lb;
    }
}

// ---------------------------------------------------------------------------
// k_wx: all weight transpose+split work in ONE launch. [identical to R8]
// ---------------------------------------------------------------------------
__global__ __launch_bounds__(256) void k_wx(const float* W_l, const float* W_r,
                                            const float* W1, const float* W2,
                                            bf16* wlh, bf16* wll,
                                            bf16* wrh, bf16* wrl,
                                            bf16* w1h, bf16* w1l,
                                            bf16* w2h, bf16* w2l) {
    int tid = blockIdx.x * blockDim.x + threadIdx.x;   // 98304 threads
    unsigned short h, l;
    if (tid < 32768) {
        int m = tid >> 14, t = tid & 16383;
        int c = t >> 7, k = t & 127;
        hilo((m ? W_r : W_l)[k * 128 + c], h, l);
        (m ? wrh : wlh)[t] = *(bf16*)&h;
        (m ? wrl : wll)[t] = *(bf16*)&l;
    } else if (tid < 65536) {
        int t = tid - 32768;
        int c = t >> 7, k = t & 127;
        hilo(W1[k * 256 + c], h, l);
        w1h[t] = *(bf16*)&h;
        w1l[t] = *(bf16*)&l;
    } else {
        int t = tid - 65536;
        int c = t >> 8, k = t & 255;
        hilo(W2[k * 128 + c], h, l);
        w2h[t] = *(bf16*)&h;
        w2l[t] = *(bf16*)&l;
    }
}

// ---------------------------------------------------------------------------
// k_fuse: [byte-identical to passing R8]
// ---------------------------------------------------------------------------
__global__ __launch_bounds__(256) void k_fuse(const float* edge_attr, const int* ei,
                                              float* sum_ea, int* rhist,
                                              const float* x,
                                              const bf16* wlh, const bf16* wll,
                                              const bf16* wrh, const bf16* wrl,
                                              const float* b_l, const float* b_r,
                                              bf16* xl, bf16* xr) {
    __shared__ __align__(16) float s_x[32][132];
    const int bid = blockIdx.x;
    int idx;
    bool isprep;
    if (bid < 2 * HIST_BLKS) { isprep = (bid & 1); idx = bid >> 1; }
    else { isprep = false; idx = HIST_BLKS + (bid - 2 * HIST_BLKS); }

    if (isprep) {
        int* hcnt = (int*)&s_x[0][0];
        const int t = threadIdx.x;
        if (t < 64) hcnt[t] = 0;
        __syncthreads();
        const int e0 = idx * ES;
        int e1 = e0 + ES; if (e1 > ETOT) e1 = ETOT;
        float local = 0.f;
        for (int e = e0 + t; e < e1; e += 256) {
            int dst = (e < NEDGE) ? ei[NEDGE + e] : (e - NEDGE);
            atomicAdd(&hcnt[dst >> 10], 1);
            if (e < NEDGE) local += edge_attr[e];
        }
        #pragma unroll
        for (int s = 1; s < 64; s <<= 1) local += __shfl_xor(local, s, 64);
        if ((t & 63) == 0) atomicAdd(sum_ea, local);
        __syncthreads();
        if (t < 64) rhist[idx * 64 + t] = hcnt[t];
        return;
    }

    const int tid = threadIdx.x;
    const int n0 = idx * 32;
    for (int it = 0; it < 4; ++it) {
        int idx4 = (it * 256 + tid) * 4;
        int n = idx4 >> 7, j = idx4 & 127;
        int node = n0 + n;
        float4 v = make_float4(0.f, 0.f, 0.f, 0.f);
        if (node < NODES) v = *(const float4*)(x + node * 128 + j);
        *(float4*)&s_x[n][j] = v;
    }
    __syncthreads();

    const int wv4  = tid >> 6;
    const int ln   = tid & 63;
    const int lrow = ln & 15;
    const int lk8  = (ln >> 4) << 3;
    const int m    = wv4 >> 1;
    const int cb   = (wv4 & 1) * 64;
    const bf16* Bh = m ? wrh : wlh;
    const bf16* Bl = m ? wrl : wll;
    const float* bias = m ? b_r : b_l;

    f32x4 acc[2][4];
    #pragma unroll
    for (int mt = 0; mt < 2; ++mt)
        #pragma unroll
        for (int i = 0; i < 4; ++i)
            acc[mt][i] = (f32x4){0.f, 0.f, 0.f, 0.f};
    #pragma unroll
    for (int kk = 0; kk < 4; ++kk) {
        int k0 = kk * 32 + lk8;
        float a0f[8], a1f[8];
        *(float4*)&a0f[0] = *(const float4*)&s_x[lrow][k0];
        *(float4*)&a0f[4] = *(const float4*)&s_x[lrow][k0 + 4];
        *(float4*)&a1f[0] = *(const float4*)&s_x[16 + lrow][k0];
        *(float4*)&a1f[4] = *(const float4*)&s_x[16 + lrow][k0 + 4];
        bf16x8 a0h, a0l, a1h, a1l;
        split8(a0f, a0h, a0l);
        split8(a1f, a1h, a1l);
        #pragma unroll
        for (int i = 0; i < 4; ++i) {
            int col = cb + (i << 4) + lrow;
            bf16x8 bh = *(const bf16x8*)(Bh + col * 128 + k0);
            bf16x8 bl = *(const bf16x8*)(Bl + col * 128 + k0);
            acc[0][i] = __builtin_amdgcn_mfma_f32_16x16x32_bf16(a0l, bh, acc[0][i], 0, 0, 0);
            acc[0][i] = __builtin_amdgcn_mfma_f32_16x16x32_bf16(a0h, bl, acc[0][i], 0, 0, 0);
            acc[0][i] = __builtin_amdgcn_mfma_f32_16x16x32_bf16(a0h, bh, acc[0][i], 0, 0, 0);
            acc[1][i] = __builtin_amdgcn_mfma_f32_16x16x32_bf16(a1l, bh, acc[1][i], 0, 0, 0);
            acc[1][i] = __builtin_amdgcn_mfma_f32_16x16x32_bf16(a1h, bl, acc[1][i], 0, 0, 0);
            acc[1][i] = __builtin_amdgcn_mfma_f32_16x16x32_bf16(a1h, bh, acc[1][i], 0, 0, 0);
        }
    }
    __syncthreads();
    bf16* s_o = (bf16*)&s_x[0][0];
    #pragma unroll
    for (int mt = 0; mt < 2; ++mt) {
        #pragma unroll
        for (int i = 0; i < 4; ++i) {
            int colg = cb + (i << 4) + lrow;
            float bv = bias[colg];
            #pragma unroll
            for (int r = 0; r < 4; ++r) {
                int row = (mt << 4) + ((ln >> 4) << 2) + r;
                s_o[row * 264 + m * 136 + colg] = f2bf(acc[mt][i][r] + bv);
            }
        }
    }
    __syncthreads();
    #pragma unroll
    for (int rep = 0; rep < 2; ++rep) {
        int idx2 = rep * 256 + tid;
        int row = idx2 >> 4, cc = (idx2 & 15) * 8;
        int node = n0 + row;
        if (node < NODES) {
            *(float4*)(xl + node * 128 + cc) = *(const float4*)(s_o + row * 264 + cc);
            *(float4*)(xr + node * 128 + cc) = *(const float4*)(s_o + row * 264 + 136 + cc);
        }
    }
}

// ---------------------------------------------------------------------------
// k_rscan / k_scatter / k_group: [byte-identical to passing R8]
// ---------------------------------------------------------------------------
__global__ __launch_bounds__(256) void k_rscan(int* rhist, int* base_r, int* off) {
    __shared__ int s_w[4];
    __shared__ int s_run;
    const int t = threadIdx.x, lane = t & 63, w = t >> 6;
    if (t == 0) s_run = 0;
    __syncthreads();
    for (int r = 0; r < NRANGE; ++r) {
        int v = rhist[t * 64 + r];
        int inc = v;
        #pragma unroll
        for (int d = 1; d < 64; d <<= 1) {
            int y = __shfl_up(inc, d, 64);
            if (lane >= d) inc += y;
        }
        if (lane == 63) s_w[w] = inc;
        __syncthreads();
        int woff = 0;
        #pragma unroll
        for (int ww = 0; ww < 4; ++ww) if (ww < w) woff += s_w[ww];
        int tot = s_w[0] + s_w[1] + s_w[2] + s_w[3];
        int runv = s_run;
        rhist[t * 64 + r] = runv + woff + (inc - v);
        if (t == 0) base_r[r] = runv;
        __syncthreads();
        if (t == 0) s_run = runv + tot;
        __syncthreads();
    }
    if (t == 0) { base_r[NRANGE] = ETOT; off[NODES] = ETOT; }
}

__global__ __launch_bounds__(256) void k_scatter(const int* ei, const float* edge_attr,
                                                 const float* sum_ea, const int* rhist,
                                                 uint2* tmp2) {
    __shared__ int cur[64];
    const int b = blockIdx.x, t = threadIdx.x;
    if (t < 64) cur[t] = rhist[b * 64 + t];
    __syncthreads();
    const float meanv = sum_ea[0] * (1.f / (float)NEDGE);
    const int e0 = b * ES;
    int e1 = e0 + ES; if (e1 > ETOT) e1 = ETOT;
    for (int e = e0 + t; e < e1; e += 256) {
        int src, dst; float eav;
        if (e < NEDGE) { src = ei[e]; dst = ei[NEDGE + e]; eav = edge_attr[e]; }
        else           { src = e - NEDGE; dst = src; eav = meanv; }
        int pos = atomicAdd(&cur[dst >> 10], 1);
        tmp2[pos] = make_uint2((unsigned int)dst,
                               ((unsigned int)bfbits(eav) << 16) | (unsigned int)src);
    }
}

__global__ __launch_bounds__(1024) void k_group(const uint2* tmp2, const int* base_r,
                                                int* off, unsigned int* perm) {
    __shared__ int lcnt[1024];
    __shared__ int s_w16[16];
    const int r = blockIdx.x, t = threadIdx.x;
    const int lane = t & 63, w = t >> 6;
    const int n0 = r << 10;
    const int s0 = base_r[r], s1 = base_r[r + 1];
    lcnt[t] = 0;
    __syncthreads();
    for (int i = s0 + t; i < s1; i += 1024) {
        int d = (int)tmp2[i].x;
        atomicAdd(&lcnt[d - n0], 1);
    }
    __syncthreads();
    int v = lcnt[t];
    int inc = v;
    #pragma unroll
    for (int d = 1; d < 64; d <<= 1) {
        int y = __shfl_up(inc, d, 64);
        if (lane >= d) inc += y;
    }
    if (lane == 63) s_w16[w] = inc;
    __syncthreads();
    int woff = 0;
    #pragma unroll
    for (int ww = 0; ww < 16; ++ww) if (ww < w) woff += s_w16[ww];
    int pos0 = s0 + woff + (inc - v);
    lcnt[t] = pos0;
    if (n0 + t < NODES) off[n0 + t] = pos0;
    __syncthreads();
    for (int i = s0 + t; i < s1; i += 1024) {
        uint2 p = tmp2[i];
        int pos = atomicAdd(&lcnt[(int)p.x - n0], 1);
        perm[pos] = p.y;
    }
}

// ---------------------------------------------------------------------------
// k_agge: fused k_agg + k_epi (M=32). Block owns 32 nodes; each of the 4
// waves runs 8 sequential online-softmax node loops (k_agg body verbatim),
// fuses +bias_out/elu in-register, writes rows straight to s_y in LDS.
// Then gate/FFN1/FFN2/LN proceed as the PASSING R7 M=32 epi (76us).
// Deletes the 51 MB out_agg HBM round-trip + one launch; amortizes the
// 256 KB/block weight loads and barriers over agg+epi work (R10 lesson:
// k_epi is per-block-fixed-cost-bound, so add work per block, not blocks).
// ---------------------------------------------------------------------------
__global__ __launch_bounds__(256) void k_agge(const unsigned int* xl32,
                                              const unsigned int* xr32,
                                              const unsigned int* perm, const int* off,
                                              const float* W_e, const float* att,
                                              const float* bias_out,
                                              const float* x,
                                              const float* W_gate, const float* b_gate,
                                              const bf16* w1h, const bf16* w1l,
                                              const float* b_ffn1,
                                              const bf16* w2h, const bf16* w2l,
                                              const float* b_ffn2,
                                              const float* gamma, const float* beta,
                                              float* out) {
    __shared__ __align__(16) float s_y[32][132];   // h, then y, then z (fp32)
    __shared__ __align__(16) float s_t[32][260];   // relu(ffn1) fp32 (FFN2 A)
    __shared__ float s_g[32];
    __shared__ float s_mu[32], s_rs[32];
    const int tid = threadIdx.x;
    const int lane = tid & 63;
    const int wvi  = tid >> 6;          // wave 0..3
    const int n0 = blockIdx.x * 32;
    int nn = NODES - n0; if (nn > 32) nn = 32;

    // ---- agg phase: wave wvi computes nodes n0+wvi*8 .. +7 -> elu -> s_y ----
    {
        const int c = 2 * lane;
        const float we1 = W_e[c], we2 = W_e[c + 1];
        const float a1 = att[c], a2 = att[c + 1];
        const float bo1 = bias_out[c], bo2 = bias_out[c + 1];
        for (int s = 0; s < 8; ++s) {
            const int nl = wvi * 8 + s;
            const int n = n0 + nl;
            if (n < NODES) {
                unsigned int xru = xr32[n * 64 + lane];
                float xr1 = bflo(xru), xr2 = bfhi(xru);
                int s0 = off[n], s1 = off[n + 1];
                float m = -1e30f, l = 0.f, acc1 = 0.f, acc2 = 0.f;
                int j = s0;
                for (; j + 4 <= s1; j += 4) {
                    unsigned int u0 = perm[j];
                    unsigned int u1 = perm[j + 1];
                    unsigned int u2 = perm[j + 2];
                    unsigned int u3 = perm[j + 3];
                    unsigned int g0 = xl32[(u0 & 0xffffu) * 64 + lane];
                    unsigned int g1 = xl32[(u1 & 0xffffu) * 64 + lane];
                    unsigned int g2 = xl32[(u2 & 0xffffu) * 64 + lane];
                    unsigned int g3 = xl32[(u3 & 0xffffu) * 64 + lane];
                    float e0 = bfhi(u0), e1 = bfhi(u1), e2 = bfhi(u2), e3 = bfhi(u3);
                    float x01 = bflo(g0), x02 = bfhi(g0);
                    float x11 = bflo(g1), x12 = bfhi(g1);
                    float x21 = bflo(g2), x22 = bfhi(g2);
                    float x31 = bflo(g3), x32 = bfhi(g3);
                    float p0, p1, p2, p3;
                    {
                        float v1 = x01 + xr1 + e0 * we1, v2 = x02 + xr2 + e0 * we2;
                        v1 = (v1 > 0.f) ? v1 : 0.2f * v1;
                        v2 = (v2 > 0.f) ? v2 : 0.2f * v2;
                        p0 = v1 * a1 + v2 * a2;
                    }
                    {
                        float v1 = x11 + xr1 + e1 * we1, v2 = x12 + xr2 + e1 * we2;
                        v1 = (v1 > 0.f) ? v1 : 0.2f * v1;
                        v2 = (v2 > 0.f) ? v2 : 0.2f * v2;
                        p1 = v1 * a1 + v2 * a2;
                    }
                    {
                        float v1 = x21 + xr1 + e2 * we1, v2 = x22 + xr2 + e2 * we2;
                        v1 = (v1 > 0.f) ? v1 : 0.2f * v1;
                        v2 = (v2 > 0.f) ? v2 : 0.2f * v2;
                        p2 = v1 * a1 + v2 * a2;
                    }
                    {
                        float v1 = x31 + xr1 + e3 * we1, v2 = x32 + xr2 + e3 * we2;
                        v1 = (v1 > 0.f) ? v1 : 0.2f * v1;
                        v2 = (v2 > 0.f) ? v2 : 0.2f * v2;
                        p3 = v1 * a1 + v2 * a2;
                    }
                    p0 += __shfl_xor(p0, 1, 64); p1 += __shfl_xor(p1, 1, 64);
                    p2 += __shfl_xor(p2, 1, 64); p3 += __shfl_xor(p3, 1, 64);
                    p0 += __shfl_xor(p0, 2, 64); p1 += __shfl_xor(p1, 2, 64);
                    p2 += __shfl_xor(p2, 2, 64); p3 += __shfl_xor(p3, 2, 64);
                    p0 += __shfl_xor(p0, 4, 64); p1 += __shfl_xor(p1, 4, 64);
                    p2 += __shfl_xor(p2, 4, 64); p3 += __shfl_xor(p3, 4, 64);
                    p0 += __shfl_xor(p0, 8, 64); p1 += __shfl_xor(p1, 8, 64);
                    p2 += __shfl_xor(p2, 8, 64); p3 += __shfl_xor(p3, 8, 64);
                    float nm = fmaxf(fmaxf(m, fmaxf(p0, p1)), fmaxf(p2, p3));
                    float sc = __expf(m - nm);
                    float E0 = __expf(p0 - nm);
                    float E1 = __expf(p1 - nm);
                    float E2 = __expf(p2 - nm);
                    float E3 = __expf(p3 - nm);
                    l = l * sc + E0 + E1 + E2 + E3;
                    acc1 = acc1 * sc + E0 * x01 + E1 * x11 + E2 * x21 + E3 * x31;
                    acc2 = acc2 * sc + E0 * x02 + E1 * x12 + E2 * x22 + E3 * x32;
                    m = nm;
                }
                for (; j < s1; ++j) {
                    unsigned int u0 = perm[j];
                    unsigned int g0 = xl32[(u0 & 0xffffu) * 64 + lane];
                    float e0 = bfhi(u0);
                    float x01 = bflo(g0), x02 = bfhi(g0);
                    float v1 = x01 + xr1 + e0 * we1, v2 = x02 + xr2 + e0 * we2;
                    v1 = (v1 > 0.f) ? v1 : 0.2f * v1;
                    v2 = (v2 > 0.f) ? v2 : 0.2f * v2;
                    float p = v1 * a1 + v2 * a2;
                    p += __shfl_xor(p, 1, 64);
                    p += __shfl_xor(p, 2, 64);
                    p += __shfl_xor(p, 4, 64);
                    p += __shfl_xor(p, 8, 64);
                    float nm = fmaxf(m, p);
                    float sc = __expf(m - nm);
                    float ee = __expf(p - nm);
                    l = l * sc + ee;
                    acc1 = acc1 * sc + ee * x01;
                    acc2 = acc2 * sc + ee * x02;
                    m = nm;
                }
                float inv = 1.f / fmaxf(l, 1e-30f);
                float r1 = acc1 * inv + bo1;
                float r2 = acc2 * inv + bo2;
                r1 = (r1 > 0.f) ? r1 : (__expf(r1) - 1.f);
                r2 = (r2 > 0.f) ? r2 : (__expf(r2) - 1.f);
                *(float2*)&s_y[nl][c] = make_float2(r1, r2);
            } else {
                *(float2*)&s_y[nl][c] = make_float2(0.f, 0.f);
            }
        }
    }
    __syncthreads();
    // gate: 8 threads per node [R7 verbatim]
    {
        int n = tid >> 3, kb = (tid & 7) * 16;
        float g = 0.f;
        #pragma unroll
        for (int k = 0; k < 16; k += 4) {
            float4 w = *(const float4*)(W_gate + kb + k);
            float4 h = *(const float4*)&s_y[n][kb + k];
            g += h.x * w.x + h.y * w.y + h.z * w.z + h.w * w.w;
        }
        g += __shfl_xor(g, 1, 64);
        g += __shfl_xor(g, 2, 64);
        g += __shfl_xor(g, 4, 64);
        if ((tid & 7) == 0) s_g[n] = 1.f / (1.f + __expf(-(g + b_gate[0])));
    }
    __syncthreads();
    // y = g*h + (1-g)*x -> s_y (fp32) [R7 verbatim]
    for (int it = 0; it < 4; ++it) {
        int idx4 = (it * 256 + tid) * 4;
        int n = idx4 >> 7, j = idx4 & 127;
        if (n < nn) {
            float g = s_g[n];
            float4 xv = *(const float4*)(x + (n0 + n) * 128 + j);
            float4 h = *(float4*)&s_y[n][j];
            h.x = g * h.x + (1.f - g) * xv.x;
            h.y = g * h.y + (1.f - g) * xv.y;
            h.z = g * h.z + (1.f - g) * xv.z;
            h.w = g * h.w + (1.f - g) * xv.w;
            *(float4*)&s_y[n][j] = h;
        }
    }
    __syncthreads();

    const int wv   = wvi;
    const int ln   = lane;
    const int lrow = ln & 15;           // A row / B,D col within tile
    const int lk8  = (ln >> 4) << 3;    // k chunk base: 0,8,16,24

    // FFN1: t = relu(y @ W1 + b1). M=32 (2 tiles), per-wave N=64, K=128.
    f32x4 acc1[2][4];
    #pragma unroll
    for (int mt = 0; mt < 2; ++mt)
        #pragma unroll
        for (int i = 0; i < 4; ++i)
            acc1[mt][i] = (f32x4){0.f, 0.f, 0.f, 0.f};
    #pragma unroll
    for (int kk = 0; kk < 4; ++kk) {
        int k0 = kk * 32 + lk8;
        float a0f[8], a1f[8];
        *(float4*)&a0f[0] = *(const float4*)&s_y[lrow][k0];
        *(float4*)&a0f[4] = *(const float4*)&s_y[lrow][k0 + 4];
        *(float4*)&a1f[0] = *(const float4*)&s_y[16 + lrow][k0];
        *(float4*)&a1f[4] = *(const float4*)&s_y[16 + lrow][k0 + 4];
        bf16x8 a0h, a0l, a1h, a1l;
        split8(a0f, a0h, a0l);
        split8(a1f, a1h, a1l);
        #pragma unroll
        for (int i = 0; i < 4; ++i) {
            int col = (wv << 6) + (i << 4) + lrow;
            bf16x8 bh = *(const bf16x8*)(w1h + col * 128 + k0);
            bf16x8 bl = *(const bf16x8*)(w1l + col * 128 + k0);
            acc1[0][i] = __builtin_amdgcn_mfma_f32_16x16x32_bf16(a0l, bh, acc1[0][i], 0, 0, 0);
            acc1[0][i] = __builtin_amdgcn_mfma_f32_16x16x32_bf16(a0h, bl, acc1[0][i], 0, 0, 0);
            acc1[0][i] = __builtin_amdgcn_mfma_f32_16x16x32_bf16(a0h, bh, acc1[0][i], 0, 0, 0);
            acc1[1][i] = __builtin_amdgcn_mfma_f32_16x16x32_bf16(a1l, bh, acc1[1][i], 0, 0, 0);
            acc1[1][i] = __builtin_amdgcn_mfma_f32_16x16x32_bf16(a1h, bl, acc1[1][i], 0, 0, 0);
            acc1[1][i] = __builtin_amdgcn_mfma_f32_16x16x32_bf16(a1h, bh, acc1[1][i], 0, 0, 0);
        }
    }
    // epilogue: +b1, relu -> s_t (fp32) [R7 verbatim]
    #pragma unroll
    for (int mt = 0; mt < 2; ++mt) {
        #pragma unroll
        for (int i = 0; i < 4; ++i) {
            int col = (wv << 6) + (i << 4) + lrow;
            float bv = b_ffn1[col];
            #pragma unroll
            for (int r = 0; r < 4; ++r) {
                int row = (mt << 4) + ((ln >> 4) << 2) + r;
                s_t[row][col] = fmaxf(acc1[mt][i][r] + bv, 0.f);
            }
        }
    }
    __syncthreads();

    // FFN2: ffn = t @ W2 + b2. M=32 (2 tiles), per-wave N=32, K=256.
    f32x4 acc2[2][2];
    #pragma unroll
    for (int mt = 0; mt < 2; ++mt)
        #pragma unroll
        for (int c = 0; c < 2; ++c)
            acc2[mt][c] = (f32x4){0.f, 0.f, 0.f, 0.f};
    #pragma unroll
    for (int kk = 0; kk < 8; ++kk) {
        int k0 = kk * 32 + lk8;
        float a0f[8], a1f[8];
        *(float4*)&a0f[0] = *(const float4*)&s_t[lrow][k0];
        *(float4*)&a0f[4] = *(const float4*)&s_t[lrow][k0 + 4];
        *(float4*)&a1f[0] = *(const float4*)&s_t[16 + lrow][k0];
        *(float4*)&a1f[4] = *(const float4*)&s_t[16 + lrow][k0 + 4];
        bf16x8 a0h, a0l, a1h, a1l;
        split8(a0f, a0h, a0l);
        split8(a1f, a1h, a1l);
        #pragma unroll
        for (int c = 0; c < 2; ++c) {
            int col = (wv << 5) + (c << 4) + lrow;
            bf16x8 bh = *(const bf16x8*)(w2h + col * 256 + k0);
            bf16x8 bl = *(const bf16x8*)(w2l + col * 256 + k0);
            acc2[0][c] = __builtin_amdgcn_mfma_f32_16x16x32_bf16(a0l, bh, acc2[0][c], 0, 0, 0);
            acc2[0][c] = __builtin_amdgcn_mfma_f32_16x16x32_bf16(a0h, bl, acc2[0][c], 0, 0, 0);
            acc2[0][c] = __builtin_amdgcn_mfma_f32_16x16x32_bf16(a0h, bh, acc2[0][c], 0, 0, 0);
            acc2[1][c] = __builtin_amdgcn_mfma_f32_16x16x32_bf16(a1l, bh, acc2[1][c], 0, 0, 0);
            acc2[1][c] = __builtin_amdgcn_mfma_f32_16x16x32_bf16(a1h, bl, acc2[1][c], 0, 0, 0);
            acc2[1][c] = __builtin_amdgcn_mfma_f32_16x16x32_bf16(a1h, bh, acc2[1][c], 0, 0, 0);
        }
    }
    // epilogue: y += ffn + b2 [R7 verbatim]
    #pragma unroll
    for (int mt = 0; mt < 2; ++mt) {
        #pragma unroll
        for (int c = 0; c < 2; ++c) {
            int col = (wv << 5) + (c << 4) + lrow;
            float bv = b_ffn2[col];
            #pragma unroll
            for (int r = 0; r < 4; ++r) {
                int row = (mt << 4) + ((ln >> 4) << 2) + r;
                s_y[row][col] += acc2[mt][c][r] + bv;
            }
        }
    }
    __syncthreads();
    // LayerNorm stats: 8 threads per node [R7 verbatim]
    {
        int n = tid >> 3, kb = (tid & 7) * 16;
        float s = 0.f, ss = 0.f;
        #pragma unroll
        for (int k = 0; k < 16; k += 4) {
            float4 v = *(const float4*)&s_y[n][kb + k];
            s  += v.x + v.y + v.z + v.w;
            ss += v.x * v.x + v.y * v.y + v.z * v.z + v.w * v.w;
        }
        s  += __shfl_xor(s, 1, 64);  ss += __shfl_xor(ss, 1, 64);
        s  += __shfl_xor(s, 2, 64);  ss += __shfl_xor(ss, 2, 64);
        s  += __shfl_xor(s, 4, 64);  ss += __shfl_xor(ss, 4, 64);
        if ((tid & 7) == 0) {
            float mu = s * (1.f / 128.f);
            float var = ss * (1.f / 128.f) - mu * mu;
            s_mu[n] = mu;
            s_rs[n] = rsqrtf(fmaxf(var, 0.f) + 1e-5f);
        }
    }
    __syncthreads();
    // normalize + store (fp32) [R7 verbatim]
    for (int it = 0; it < 4; ++it) {
        int idx4 = (it * 256 + tid) * 4;
        int n = idx4 >> 7, j = idx4 & 127;
        if (n < nn) {
            float mu = s_mu[n], rs = s_rs[n];
            float4 gv = *(const float4*)(gamma + j);
            float4 bv = *(const float4*)(beta + j);
            float4 v = *(const float4*)&s_y[n][j];
            float4 o;
            o.x = (v.x - mu) * rs * gv.x + bv.x;
            o.y = (v.y - mu) * rs * gv.y + bv.y;
            o.z = (v.z - mu) * rs * gv.z + bv.z;
            o.w = (v.w - mu) * rs * gv.w + bv.w;
            *(float4*)(out + (n0 + n) * 128 + j) = o;
        }
    }
}

// ---------------------------------------------------------------------------
extern "C" void kernel_launch(void* const* d_in, const int* in_sizes, int n_in,
                              void* d_out, int out_size, void* d_ws, size_t ws_size,
                              hipStream_t stream) {
    const float* x         = (const float*)d_in[0];
    const float* edge_attr = (const float*)d_in[1];
    const int* edge_index  = (const int*)d_in[17];
    float* out = (float*)d_out;

    char* base = (char*)d_ws;
    // workspace layout (29,600,064 B total, hardware-proven extents):
    float* sum_ea  = (float*)(base + 16);                     // 16 B
    int*   rhist   = (int*)  (base + 32);                     // 65536
    bf16*  w1t_hi  = (bf16*) (base + 32 + 65536);             // 65536 (disjoint from rhist)
    bf16*  w1t_lo  = (bf16*) (base + 32 + 131072);            // 65536 -> ends 196640 < 200032
    int*   off     = (int*)  (base + 200032);                 // 200004 (+pad)
    int*   base_r  = (int*)  (base + 400064);                 // 50 ints (pad to 256)
    bf16*  w2t_hi  = (bf16*) (base + 400064 + 256);           // 65536 (disjoint from base_r)
    bf16*  w2t_lo  = (bf16*) (base + 400064 + 256 + 65536);   // ends 531392 < 600064
    unsigned int* perm = (unsigned int*)(base + 600064);      // 3400000
    bf16*  xl      = (bf16*) (base + 4000064);                // 12800000
    bf16*  xr      = (bf16*) (base + 16800064);               // 12800000
    // xform weight split pairs: perm head +1024 (consumed by k_fuse, dead
    // before k_group writes perm). 4 x 32768 B.
    bf16*  wxlh    = (bf16*) (base + 600064 + 1024);
    bf16*  wxll    = (bf16*) (base + 600064 + 1024 + 32768);
    bf16*  wxrh    = (bf16*) (base + 600064 + 1024 + 65536);
    bf16*  wxrl    = (bf16*) (base + 600064 + 1024 + 98304);
    // range-partitioned (dst,payload) pairs: head of d_out (dead until k_agge).
    uint2* tmp2    = (uint2*)d_out;                           // 6.8 MB

    hipMemsetAsync(sum_ea, 0, 16, stream);

    const int NTILES = (NODES + 31) / 32;  // 1563

    k_wx      <<<384, 256, 0, stream>>>((const float*)d_in[2], (const float*)d_in[4],
                                        (const float*)d_in[11], (const float*)d_in[13],
                                        wxlh, wxll, wxrh, wxrl,
                                        w1t_hi, w1t_lo, w2t_hi, w2t_lo);
    k_fuse    <<<FUSE_GRID, 256, 0, stream>>>(edge_attr, edge_index, sum_ea, rhist,
                                              x, wxlh, wxll, wxrh, wxrl,
                                              (const float*)d_in[3], (const float*)d_in[5],
                                              xl, xr);
    k_rscan   <<<1, 256, 0, stream>>>(rhist, base_r, off);
    k_scatter <<<SB, 256, 0, stream>>>(edge_index, edge_attr, sum_ea, rhist, tmp2);
    k_group   <<<NRANGE, 1024, 0, stream>>>(tmp2, base_r, off, perm);
    k_agge    <<<NTILES, 256, 0, stream>>>((const unsigned int*)xl,
                                           (const unsigned int*)xr,
                                           perm, off,
                                           (const float*)d_in[6], (const float*)d_in[7],
                                           (const float*)d_in[8], x,
                                           (const float*)d_in[9], (const float*)d_in[10],
                                           w1t_hi, w1t_lo, (const float*)d_in[12],
                                           w2t_hi, w2t_lo, (const float*)d_in[14],
                                           (const float*)d_in[15], (const float*)d_in[16],
                                           out);
}

// Round 12
// 349.890 us; speedup vs baseline: 1.1183x; 1.1183x over previous
//
#include <hip/hip_runtime.h>
#include <hip/hip_bf16.h>

#define NODES 50000
#define NEDGE 800000
#define ETOT  850000   /* NEDGE + NODES self loops */

#define NRANGE 49            /* ceil(NODES/1024) dst ranges */
#define SB 256               /* scatter/hist blocks */
#define ES ((ETOT + SB - 1) / SB)   /* 3321 edges per slice */

#define XF_TILES 1563        /* ceil(NODES/32) */
#define HIST_BLKS 256
#define FUSE_GRID (2 * HIST_BLKS + (XF_TILES - HIST_BLKS))  /* 1819 */

typedef __hip_bfloat16 bf16;
typedef __attribute__((ext_vector_type(8))) short bf16x8;
typedef __attribute__((ext_vector_type(4))) float f32x4;

__device__ __forceinline__ bf16 f2bf(float v) { return __float2bfloat16(v); }
__device__ __forceinline__ float bflo(unsigned int v) { return __uint_as_float(v << 16); }
__device__ __forceinline__ float bfhi(unsigned int v) { return __uint_as_float(v & 0xffff0000u); }

__device__ __forceinline__ unsigned int pack2(float a, float b) {
    bf16 x = f2bf(a), y = f2bf(b);
    unsigned short xs = *reinterpret_cast<unsigned short*>(&x);
    unsigned short ys = *reinterpret_cast<unsigned short*>(&y);
    return ((unsigned int)ys << 16) | (unsigned int)xs;
}

__device__ __forceinline__ unsigned short bfbits(float v) {
    bf16 x = f2bf(v);
    return *reinterpret_cast<unsigned short*>(&x);
}

// Dekker split: hi = bf16(v), lo = bf16(v - float(hi))
__device__ __forceinline__ void hilo(float v, unsigned short& h, unsigned short& l) {
    h = bfbits(v);
    float hv = __uint_as_float((unsigned int)h << 16);
    l = bfbits(v - hv);
}

// split 8 fp32 -> hi/lo bf16x8
__device__ __forceinline__ void split8(const float* v, bf16x8& hi, bf16x8& lo) {
    #pragma unroll
    for (int e = 0; e < 8; ++e) {
        unsigned short hb, lb;
        hilo(v[e], hb, lb);
        ((short*)&hi)[e] = (short)hb;
        ((short*)&lo)[e] = (short)lb;
    }
}

// ---------------------------------------------------------------------------
// k_wx: all weight transpose+split work in ONE launch. [identical to R8]
// ---------------------------------------------------------------------------
__global__ __launch_bounds__(256) void k_wx(const float* W_l, const float* W_r,
                                            const float* W1, const float* W2,
                                            bf16* wlh, bf16* wll,
                                            bf16* wrh, bf16* wrl,
                                            bf16* w1h, bf16* w1l,
                                            bf16* w2h, bf16* w2l) {
    int tid = blockIdx.x * blockDim.x + threadIdx.x;   // 98304 threads
    unsigned short h, l;
    if (tid < 32768) {
        int m = tid >> 14, t = tid & 16383;
        int c = t >> 7, k = t & 127;
        hilo((m ? W_r : W_l)[k * 128 + c], h, l);
        (m ? wrh : wlh)[t] = *(bf16*)&h;
        (m ? wrl : wll)[t] = *(bf16*)&l;
    } else if (tid < 65536) {
        int t = tid - 32768;
        int c = t >> 7, k = t & 127;
        hilo(W1[k * 256 + c], h, l);
        w1h[t] = *(bf16*)&h;
        w1l[t] = *(bf16*)&l;
    } else {
        int t = tid - 65536;
        int c = t >> 8, k = t & 255;
        hilo(W2[k * 128 + c], h, l);
        w2h[t] = *(bf16*)&h;
        w2l[t] = *(bf16*)&l;
    }
}

// ---------------------------------------------------------------------------
// k_fuse: [byte-identical to passing R8]
// ---------------------------------------------------------------------------
__global__ __launch_bounds__(256) void k_fuse(const float* edge_attr, const int* ei,
                                              float* sum_ea, int* rhist,
                                              const float* x,
                                              const bf16* wlh, const bf16* wll,
                                              const bf16* wrh, const bf16* wrl,
                                              const float* b_l, const float* b_r,
                                              bf16* xl, bf16* xr) {
    __shared__ __align__(16) float s_x[32][132];
    const int bid = blockIdx.x;
    int idx;
    bool isprep;
    if (bid < 2 * HIST_BLKS) { isprep = (bid & 1); idx = bid >> 1; }
    else { isprep = false; idx = HIST_BLKS + (bid - 2 * HIST_BLKS); }

    if (isprep) {
        int* hcnt = (int*)&s_x[0][0];
        const int t = threadIdx.x;
        if (t < 64) hcnt[t] = 0;
        __syncthreads();
        const int e0 = idx * ES;
        int e1 = e0 + ES; if (e1 > ETOT) e1 = ETOT;
        float local = 0.f;
        for (int e = e0 + t; e < e1; e += 256) {
            int dst = (e < NEDGE) ? ei[NEDGE + e] : (e - NEDGE);
            atomicAdd(&hcnt[dst >> 10], 1);
            if (e < NEDGE) local += edge_attr[e];
        }
        #pragma unroll
        for (int s = 1; s < 64; s <<= 1) local += __shfl_xor(local, s, 64);
        if ((t & 63) == 0) atomicAdd(sum_ea, local);
        __syncthreads();
        if (t < 64) rhist[idx * 64 + t] = hcnt[t];
        return;
    }

    const int tid = threadIdx.x;
    const int n0 = idx * 32;
    for (int it = 0; it < 4; ++it) {
        int idx4 = (it * 256 + tid) * 4;
        int n = idx4 >> 7, j = idx4 & 127;
        int node = n0 + n;
        float4 v = make_float4(0.f, 0.f, 0.f, 0.f);
        if (node < NODES) v = *(const float4*)(x + node * 128 + j);
        *(float4*)&s_x[n][j] = v;
    }
    __syncthreads();

    const int wv4  = tid >> 6;
    const int ln   = tid & 63;
    const int lrow = ln & 15;
    const int lk8  = (ln >> 4) << 3;
    const int m    = wv4 >> 1;
    const int cb   = (wv4 & 1) * 64;
    const bf16* Bh = m ? wrh : wlh;
    const bf16* Bl = m ? wrl : wll;
    const float* bias = m ? b_r : b_l;

    f32x4 acc[2][4];
    #pragma unroll
    for (int mt = 0; mt < 2; ++mt)
        #pragma unroll
        for (int i = 0; i < 4; ++i)
            acc[mt][i] = (f32x4){0.f, 0.f, 0.f, 0.f};
    #pragma unroll
    for (int kk = 0; kk < 4; ++kk) {
        int k0 = kk * 32 + lk8;
        float a0f[8], a1f[8];
        *(float4*)&a0f[0] = *(const float4*)&s_x[lrow][k0];
        *(float4*)&a0f[4] = *(const float4*)&s_x[lrow][k0 + 4];
        *(float4*)&a1f[0] = *(const float4*)&s_x[16 + lrow][k0];
        *(float4*)&a1f[4] = *(const float4*)&s_x[16 + lrow][k0 + 4];
        bf16x8 a0h, a0l, a1h, a1l;
        split8(a0f, a0h, a0l);
        split8(a1f, a1h, a1l);
        #pragma unroll
        for (int i = 0; i < 4; ++i) {
            int col = cb + (i << 4) + lrow;
            bf16x8 bh = *(const bf16x8*)(Bh + col * 128 + k0);
            bf16x8 bl = *(const bf16x8*)(Bl + col * 128 + k0);
            acc[0][i] = __builtin_amdgcn_mfma_f32_16x16x32_bf16(a0l, bh, acc[0][i], 0, 0, 0);
            acc[0][i] = __builtin_amdgcn_mfma_f32_16x16x32_bf16(a0h, bl, acc[0][i], 0, 0, 0);
            acc[0][i] = __builtin_amdgcn_mfma_f32_16x16x32_bf16(a0h, bh, acc[0][i], 0, 0, 0);
            acc[1][i] = __builtin_amdgcn_mfma_f32_16x16x32_bf16(a1l, bh, acc[1][i], 0, 0, 0);
            acc[1][i] = __builtin_amdgcn_mfma_f32_16x16x32_bf16(a1h, bl, acc[1][i], 0, 0, 0);
            acc[1][i] = __builtin_amdgcn_mfma_f32_16x16x32_bf16(a1h, bh, acc[1][i], 0, 0, 0);
        }
    }
    __syncthreads();
    bf16* s_o = (bf16*)&s_x[0][0];
    #pragma unroll
    for (int mt = 0; mt < 2; ++mt) {
        #pragma unroll
        for (int i = 0; i < 4; ++i) {
            int colg = cb + (i << 4) + lrow;
            float bv = bias[colg];
            #pragma unroll
            for (int r = 0; r < 4; ++r) {
                int row = (mt << 4) + ((ln >> 4) << 2) + r;
                s_o[row * 264 + m * 136 + colg] = f2bf(acc[mt][i][r] + bv);
            }
        }
    }
    __syncthreads();
    #pragma unroll
    for (int rep = 0; rep < 2; ++rep) {
        int idx2 = rep * 256 + tid;
        int row = idx2 >> 4, cc = (idx2 & 15) * 8;
        int node = n0 + row;
        if (node < NODES) {
            *(float4*)(xl + node * 128 + cc) = *(const float4*)(s_o + row * 264 + cc);
            *(float4*)(xr + node * 128 + cc) = *(const float4*)(s_o + row * 264 + 136 + cc);
        }
    }
}

// ---------------------------------------------------------------------------
// k_rscan / k_scatter / k_group: [byte-identical to passing R8]
// ---------------------------------------------------------------------------
__global__ __launch_bounds__(256) void k_rscan(int* rhist, int* base_r, int* off) {
    __shared__ int s_w[4];
    __shared__ int s_run;
    const int t = threadIdx.x, lane = t & 63, w = t >> 6;
    if (t == 0) s_run = 0;
    __syncthreads();
    for (int r = 0; r < NRANGE; ++r) {
        int v = rhist[t * 64 + r];
        int inc = v;
        #pragma unroll
        for (int d = 1; d < 64; d <<= 1) {
            int y = __shfl_up(inc, d, 64);
            if (lane >= d) inc += y;
        }
        if (lane == 63) s_w[w] = inc;
        __syncthreads();
        int woff = 0;
        #pragma unroll
        for (int ww = 0; ww < 4; ++ww) if (ww < w) woff += s_w[ww];
        int tot = s_w[0] + s_w[1] + s_w[2] + s_w[3];
        int runv = s_run;
        rhist[t * 64 + r] = runv + woff + (inc - v);
        if (t == 0) base_r[r] = runv;
        __syncthreads();
        if (t == 0) s_run = runv + tot;
        __syncthreads();
    }
    if (t == 0) { base_r[NRANGE] = ETOT; off[NODES] = ETOT; }
}

__global__ __launch_bounds__(256) void k_scatter(const int* ei, const float* edge_attr,
                                                 const float* sum_ea, const int* rhist,
                                                 uint2* tmp2) {
    __shared__ int cur[64];
    const int b = blockIdx.x, t = threadIdx.x;
    if (t < 64) cur[t] = rhist[b * 64 + t];
    __syncthreads();
    const float meanv = sum_ea[0] * (1.f / (float)NEDGE);
    const int e0 = b * ES;
    int e1 = e0 + ES; if (e1 > ETOT) e1 = ETOT;
    for (int e = e0 + t; e < e1; e += 256) {
        int src, dst; float eav;
        if (e < NEDGE) { src = ei[e]; dst = ei[NEDGE + e]; eav = edge_attr[e]; }
        else           { src = e - NEDGE; dst = src; eav = meanv; }
        int pos = atomicAdd(&cur[dst >> 10], 1);
        tmp2[pos] = make_uint2((unsigned int)dst,
                               ((unsigned int)bfbits(eav) << 16) | (unsigned int)src);
    }
}

__global__ __launch_bounds__(1024) void k_group(const uint2* tmp2, const int* base_r,
                                                int* off, unsigned int* perm) {
    __shared__ int lcnt[1024];
    __shared__ int s_w16[16];
    const int r = blockIdx.x, t = threadIdx.x;
    const int lane = t & 63, w = t >> 6;
    const int n0 = r << 10;
    const int s0 = base_r[r], s1 = base_r[r + 1];
    lcnt[t] = 0;
    __syncthreads();
    for (int i = s0 + t; i < s1; i += 1024) {
        int d = (int)tmp2[i].x;
        atomicAdd(&lcnt[d - n0], 1);
    }
    __syncthreads();
    int v = lcnt[t];
    int inc = v;
    #pragma unroll
    for (int d = 1; d < 64; d <<= 1) {
        int y = __shfl_up(inc, d, 64);
        if (lane >= d) inc += y;
    }
    if (lane == 63) s_w16[w] = inc;
    __syncthreads();
    int woff = 0;
    #pragma unroll
    for (int ww = 0; ww < 16; ++ww) if (ww < w) woff += s_w16[ww];
    int pos0 = s0 + woff + (inc - v);
    lcnt[t] = pos0;
    if (n0 + t < NODES) off[n0 + t] = pos0;
    __syncthreads();
    for (int i = s0 + t; i < s1; i += 1024) {
        uint2 p = tmp2[i];
        int pos = atomicAdd(&lcnt[(int)p.x - n0], 1);
        perm[pos] = p.y;
    }
}

// ---------------------------------------------------------------------------
// k_agg: [byte-identical to passing R10]
// ---------------------------------------------------------------------------
__global__ __launch_bounds__(256) void k_agg(const unsigned int* xl32,
                                             const unsigned int* xr32,
                                             const unsigned int* perm, const int* off,
                                             const float* W_e, const float* att,
                                             float* outp) {
    const int lane = threadIdx.x & 63;
    const int wave0 = blockIdx.x * 4 + (threadIdx.x >> 6);
    const int nwaves = gridDim.x * 4;
    const int c = 2 * lane;
    const float we1 = W_e[c], we2 = W_e[c + 1];
    const float a1 = att[c], a2 = att[c + 1];
    for (int n = wave0; n < NODES; n += nwaves) {
        unsigned int xru = xr32[n * 64 + lane];
        float xr1 = bflo(xru), xr2 = bfhi(xru);
        int s0 = off[n], s1 = off[n + 1];
        float m = -1e30f, l = 0.f, acc1 = 0.f, acc2 = 0.f;
        int j = s0;
        for (; j + 4 <= s1; j += 4) {
            unsigned int u0 = perm[j];
            unsigned int u1 = perm[j + 1];
            unsigned int u2 = perm[j + 2];
            unsigned int u3 = perm[j + 3];
            unsigned int g0 = xl32[(u0 & 0xffffu) * 64 + lane];
            unsigned int g1 = xl32[(u1 & 0xffffu) * 64 + lane];
            unsigned int g2 = xl32[(u2 & 0xffffu) * 64 + lane];
            unsigned int g3 = xl32[(u3 & 0xffffu) * 64 + lane];
            float e0 = bfhi(u0), e1 = bfhi(u1), e2 = bfhi(u2), e3 = bfhi(u3);
            float x01 = bflo(g0), x02 = bfhi(g0);
            float x11 = bflo(g1), x12 = bfhi(g1);
            float x21 = bflo(g2), x22 = bfhi(g2);
            float x31 = bflo(g3), x32 = bfhi(g3);
            float p0, p1, p2, p3;
            {
                float v1 = x01 + xr1 + e0 * we1, v2 = x02 + xr2 + e0 * we2;
                v1 = (v1 > 0.f) ? v1 : 0.2f * v1;
                v2 = (v2 > 0.f) ? v2 : 0.2f * v2;
                p0 = v1 * a1 + v2 * a2;
            }
            {
                float v1 = x11 + xr1 + e1 * we1, v2 = x12 + xr2 + e1 * we2;
                v1 = (v1 > 0.f) ? v1 : 0.2f * v1;
                v2 = (v2 > 0.f) ? v2 : 0.2f * v2;
                p1 = v1 * a1 + v2 * a2;
            }
            {
                float v1 = x21 + xr1 + e2 * we1, v2 = x22 + xr2 + e2 * we2;
                v1 = (v1 > 0.f) ? v1 : 0.2f * v1;
                v2 = (v2 > 0.f) ? v2 : 0.2f * v2;
                p2 = v1 * a1 + v2 * a2;
            }
            {
                float v1 = x31 + xr1 + e3 * we1, v2 = x32 + xr2 + e3 * we2;
                v1 = (v1 > 0.f) ? v1 : 0.2f * v1;
                v2 = (v2 > 0.f) ? v2 : 0.2f * v2;
                p3 = v1 * a1 + v2 * a2;
            }
            p0 += __shfl_xor(p0, 1, 64); p1 += __shfl_xor(p1, 1, 64);
            p2 += __shfl_xor(p2, 1, 64); p3 += __shfl_xor(p3, 1, 64);
            p0 += __shfl_xor(p0, 2, 64); p1 += __shfl_xor(p1, 2, 64);
            p2 += __shfl_xor(p2, 2, 64); p3 += __shfl_xor(p3, 2, 64);
            p0 += __shfl_xor(p0, 4, 64); p1 += __shfl_xor(p1, 4, 64);
            p2 += __shfl_xor(p2, 4, 64); p3 += __shfl_xor(p3, 4, 64);
            p0 += __shfl_xor(p0, 8, 64); p1 += __shfl_xor(p1, 8, 64);
            p2 += __shfl_xor(p2, 8, 64); p3 += __shfl_xor(p3, 8, 64);
            float nm = fmaxf(fmaxf(m, fmaxf(p0, p1)), fmaxf(p2, p3));
            float sc = __expf(m - nm);
            float E0 = __expf(p0 - nm);
            float E1 = __expf(p1 - nm);
            float E2 = __expf(p2 - nm);
            float E3 = __expf(p3 - nm);
            l = l * sc + E0 + E1 + E2 + E3;
            acc1 = acc1 * sc + E0 * x01 + E1 * x11 + E2 * x21 + E3 * x31;
            acc2 = acc2 * sc + E0 * x02 + E1 * x12 + E2 * x22 + E3 * x32;
            m = nm;
        }
        for (; j < s1; ++j) {
            unsigned int u0 = perm[j];
            unsigned int g0 = xl32[(u0 & 0xffffu) * 64 + lane];
            float e0 = bfhi(u0);
            float x01 = bflo(g0), x02 = bfhi(g0);
            float v1 = x01 + xr1 + e0 * we1, v2 = x02 + xr2 + e0 * we2;
            v1 = (v1 > 0.f) ? v1 : 0.2f * v1;
            v2 = (v2 > 0.f) ? v2 : 0.2f * v2;
            float p = v1 * a1 + v2 * a2;
            p += __shfl_xor(p, 1, 64);
            p += __shfl_xor(p, 2, 64);
            p += __shfl_xor(p, 4, 64);
            p += __shfl_xor(p, 8, 64);
            float nm = fmaxf(m, p);
            float sc = __expf(m - nm);
            float ee = __expf(p - nm);
            l = l * sc + ee;
            acc1 = acc1 * sc + ee * x01;
            acc2 = acc2 * sc + ee * x02;
            m = nm;
        }
        float inv = 1.f / fmaxf(l, 1e-30f);
        *(float2*)(outp + n * 128 + c) = make_float2(acc1 * inv, acc2 * inv);
    }
}

// ---------------------------------------------------------------------------
// k_epi v5: R7's passing M=32 body with the three pre-FFN phases
// (elu -> gate -> y) collapsed into ONE wave-local phase: each wave owns 8
// whole nodes; lane holds channels (2*lane, 2*lane+1); gate reduced via
// 6-step 64-lane shfl; y written to LDS once. 3 barriers -> 1, h never
// touches LDS. FFN1/FFN2/LN byte-identical to R7 (gate dot fp32 sum order
// is the only numeric change).
// ---------------------------------------------------------------------------
__global__ __launch_bounds__(256) void k_epi(const float* out_agg, const float* x,
                                             const float* bias_out,
                                             const float* W_gate, const float* b_gate,
                                             const bf16* w1h, const bf16* w1l,
                                             const float* b_ffn1,
                                             const bf16* w2h, const bf16* w2l,
                                             const float* b_ffn2,
                                             const float* gamma, const float* beta,
                                             float* out) {
    __shared__ __align__(16) float s_y[32][132];   // y, then z (fp32)
    __shared__ __align__(16) float s_t[32][260];   // relu(ffn1) fp32 (FFN2 A)
    __shared__ float s_mu[32], s_rs[32];
    const int tid = threadIdx.x;
    const int lane = tid & 63;
    const int wvi  = tid >> 6;
    const int n0 = blockIdx.x * 32;
    int nn = NODES - n0; if (nn > 32) nn = 32;

    // ---- fused elu+gate+y: wave wvi owns nodes wvi*8..wvi*8+7 ----
    {
        const int c = 2 * lane;
        const float bo1 = bias_out[c],  bo2 = bias_out[c + 1];
        const float wg1 = W_gate[c],    wg2 = W_gate[c + 1];
        const float bg0 = b_gate[0];
        for (int s = 0; s < 8; ++s) {
            const int nl = wvi * 8 + s;
            const int n = n0 + nl;
            if (n < NODES) {
                float2 v = *(const float2*)(out_agg + n * 128 + c);
                float h1 = v.x + bo1, h2 = v.y + bo2;
                h1 = (h1 > 0.f) ? h1 : (__expf(h1) - 1.f);
                h2 = (h2 > 0.f) ? h2 : (__expf(h2) - 1.f);
                float g = h1 * wg1 + h2 * wg2;
                g += __shfl_xor(g, 1, 64);
                g += __shfl_xor(g, 2, 64);
                g += __shfl_xor(g, 4, 64);
                g += __shfl_xor(g, 8, 64);
                g += __shfl_xor(g, 16, 64);
                g += __shfl_xor(g, 32, 64);
                g = 1.f / (1.f + __expf(-(g + bg0)));
                float2 xv = *(const float2*)(x + n * 128 + c);
                float y1 = g * h1 + (1.f - g) * xv.x;
                float y2 = g * h2 + (1.f - g) * xv.y;
                *(float2*)&s_y[nl][c] = make_float2(y1, y2);
            } else {
                *(float2*)&s_y[nl][c] = make_float2(0.f, 0.f);
            }
        }
    }
    __syncthreads();

    const int wv   = wvi;
    const int ln   = lane;
    const int lrow = ln & 15;           // A row / B,D col within tile
    const int lk8  = (ln >> 4) << 3;    // k chunk base: 0,8,16,24

    // FFN1: t = relu(y @ W1 + b1). M=32 (2 tiles), per-wave N=64, K=128.
    f32x4 acc1[2][4];
    #pragma unroll
    for (int mt = 0; mt < 2; ++mt)
        #pragma unroll
        for (int i = 0; i < 4; ++i)
            acc1[mt][i] = (f32x4){0.f, 0.f, 0.f, 0.f};
    #pragma unroll
    for (int kk = 0; kk < 4; ++kk) {
        int k0 = kk * 32 + lk8;
        float a0f[8], a1f[8];
        *(float4*)&a0f[0] = *(const float4*)&s_y[lrow][k0];
        *(float4*)&a0f[4] = *(const float4*)&s_y[lrow][k0 + 4];
        *(float4*)&a1f[0] = *(const float4*)&s_y[16 + lrow][k0];
        *(float4*)&a1f[4] = *(const float4*)&s_y[16 + lrow][k0 + 4];
        bf16x8 a0h, a0l, a1h, a1l;
        split8(a0f, a0h, a0l);
        split8(a1f, a1h, a1l);
        #pragma unroll
        for (int i = 0; i < 4; ++i) {
            int col = (wv << 6) + (i << 4) + lrow;
            bf16x8 bh = *(const bf16x8*)(w1h + col * 128 + k0);
            bf16x8 bl = *(const bf16x8*)(w1l + col * 128 + k0);
            acc1[0][i] = __builtin_amdgcn_mfma_f32_16x16x32_bf16(a0l, bh, acc1[0][i], 0, 0, 0);
            acc1[0][i] = __builtin_amdgcn_mfma_f32_16x16x32_bf16(a0h, bl, acc1[0][i], 0, 0, 0);
            acc1[0][i] = __builtin_amdgcn_mfma_f32_16x16x32_bf16(a0h, bh, acc1[0][i], 0, 0, 0);
            acc1[1][i] = __builtin_amdgcn_mfma_f32_16x16x32_bf16(a1l, bh, acc1[1][i], 0, 0, 0);
            acc1[1][i] = __builtin_amdgcn_mfma_f32_16x16x32_bf16(a1h, bl, acc1[1][i], 0, 0, 0);
            acc1[1][i] = __builtin_amdgcn_mfma_f32_16x16x32_bf16(a1h, bh, acc1[1][i], 0, 0, 0);
        }
    }
    // epilogue: +b1, relu -> s_t (fp32) [R7 verbatim]
    #pragma unroll
    for (int mt = 0; mt < 2; ++mt) {
        #pragma unroll
        for (int i = 0; i < 4; ++i) {
            int col = (wv << 6) + (i << 4) + lrow;
            float bv = b_ffn1[col];
            #pragma unroll
            for (int r = 0; r < 4; ++r) {
                int row = (mt << 4) + ((ln >> 4) << 2) + r;
                s_t[row][col] = fmaxf(acc1[mt][i][r] + bv, 0.f);
            }
        }
    }
    __syncthreads();

    // FFN2: ffn = t @ W2 + b2. M=32 (2 tiles), per-wave N=32, K=256.
    f32x4 acc2[2][2];
    #pragma unroll
    for (int mt = 0; mt < 2; ++mt)
        #pragma unroll
        for (int c = 0; c < 2; ++c)
            acc2[mt][c] = (f32x4){0.f, 0.f, 0.f, 0.f};
    #pragma unroll
    for (int kk = 0; kk < 8; ++kk) {
        int k0 = kk * 32 + lk8;
        float a0f[8], a1f[8];
        *(float4*)&a0f[0] = *(const float4*)&s_t[lrow][k0];
        *(float4*)&a0f[4] = *(const float4*)&s_t[lrow][k0 + 4];
        *(float4*)&a1f[0] = *(const float4*)&s_t[16 + lrow][k0];
        *(float4*)&a1f[4] = *(const float4*)&s_t[16 + lrow][k0 + 4];
        bf16x8 a0h, a0l, a1h, a1l;
        split8(a0f, a0h, a0l);
        split8(a1f, a1h, a1l);
        #pragma unroll
        for (int c = 0; c < 2; ++c) {
            int col = (wv << 5) + (c << 4) + lrow;
            bf16x8 bh = *(const bf16x8*)(w2h + col * 256 + k0);
            bf16x8 bl = *(const bf16x8*)(w2l + col * 256 + k0);
            acc2[0][c] = __builtin_amdgcn_mfma_f32_16x16x32_bf16(a0l, bh, acc2[0][c], 0, 0, 0);
            acc2[0][c] = __builtin_amdgcn_mfma_f32_16x16x32_bf16(a0h, bl, acc2[0][c], 0, 0, 0);
            acc2[0][c] = __builtin_amdgcn_mfma_f32_16x16x32_bf16(a0h, bh, acc2[0][c], 0, 0, 0);
            acc2[1][c] = __builtin_amdgcn_mfma_f32_16x16x32_bf16(a1l, bh, acc2[1][c], 0, 0, 0);
            acc2[1][c] = __builtin_amdgcn_mfma_f32_16x16x32_bf16(a1h, bl, acc2[1][c], 0, 0, 0);
            acc2[1][c] = __builtin_amdgcn_mfma_f32_16x16x32_bf16(a1h, bh, acc2[1][c], 0, 0, 0);
        }
    }
    // epilogue: y += ffn + b2 [R7 verbatim]
    #pragma unroll
    for (int mt = 0; mt < 2; ++mt) {
        #pragma unroll
        for (int c = 0; c < 2; ++c) {
            int col = (wv << 5) + (c << 4) + lrow;
            float bv = b_ffn2[col];
            #pragma unroll
            for (int r = 0; r < 4; ++r) {
                int row = (mt << 4) + ((ln >> 4) << 2) + r;
                s_y[row][col] += acc2[mt][c][r] + bv;
            }
        }
    }
    __syncthreads();
    // LayerNorm stats: 8 threads per node [R7 verbatim]
    {
        int n = tid >> 3, kb = (tid & 7) * 16;
        float s = 0.f, ss = 0.f;
        #pragma unroll
        for (int k = 0; k < 16; k += 4) {
            float4 v = *(const float4*)&s_y[n][kb + k];
            s  += v.x + v.y + v.z + v.w;
            ss += v.x * v.x + v.y * v.y + v.z * v.z + v.w * v.w;
        }
        s  += __shfl_xor(s, 1, 64);  ss += __shfl_xor(ss, 1, 64);
        s  += __shfl_xor(s, 2, 64);  ss += __shfl_xor(ss, 2, 64);
        s  += __shfl_xor(s, 4, 64);  ss += __shfl_xor(ss, 4, 64);
        if ((tid & 7) == 0) {
            float mu = s * (1.f / 128.f);
            float var = ss * (1.f / 128.f) - mu * mu;
            s_mu[n] = mu;
            s_rs[n] = rsqrtf(fmaxf(var, 0.f) + 1e-5f);
        }
    }
    __syncthreads();
    // normalize + store (fp32) [R7 verbatim]
    for (int it = 0; it < 4; ++it) {
        int idx4 = (it * 256 + tid) * 4;
        int n = idx4 >> 7, j = idx4 & 127;
        if (n < nn) {
            float mu = s_mu[n], rs = s_rs[n];
            float4 gv = *(const float4*)(gamma + j);
            float4 bv = *(const float4*)(beta + j);
            float4 v = *(const float4*)&s_y[n][j];
            float4 o;
            o.x = (v.x - mu) * rs * gv.x + bv.x;
            o.y = (v.y - mu) * rs * gv.y + bv.y;
            o.z = (v.z - mu) * rs * gv.z + bv.z;
            o.w = (v.w - mu) * rs * gv.w + bv.w;
            *(float4*)(out + (n0 + n) * 128 + j) = o;
        }
    }
}

// ---------------------------------------------------------------------------
extern "C" void kernel_launch(void* const* d_in, const int* in_sizes, int n_in,
                              void* d_out, int out_size, void* d_ws, size_t ws_size,
                              hipStream_t stream) {
    const float* x         = (const float*)d_in[0];
    const float* edge_attr = (const float*)d_in[1];
    const int* edge_index  = (const int*)d_in[17];
    float* out = (float*)d_out;

    char* base = (char*)d_ws;
    // workspace layout (29,600,064 B total, hardware-proven extents):
    float* sum_ea  = (float*)(base + 16);                     // 16 B
    int*   rhist   = (int*)  (base + 32);                     // 65536
    bf16*  w1t_hi  = (bf16*) (base + 32 + 65536);             // 65536 (disjoint from rhist)
    bf16*  w1t_lo  = (bf16*) (base + 32 + 131072);            // 65536 -> ends 196640 < 200032
    int*   off     = (int*)  (base + 200032);                 // 200004 (+pad)
    int*   base_r  = (int*)  (base + 400064);                 // 50 ints (pad to 256)
    bf16*  w2t_hi  = (bf16*) (base + 400064 + 256);           // 65536 (disjoint from base_r)
    bf16*  w2t_lo  = (bf16*) (base + 400064 + 256 + 65536);   // ends 531392 < 600064
    unsigned int* perm = (unsigned int*)(base + 600064);      // 3400000
    bf16*  xl      = (bf16*) (base + 4000064);                // 12800000
    bf16*  xr      = (bf16*) (base + 16800064);               // 12800000
    // xform weight split pairs: perm head +1024 (consumed by k_fuse, dead
    // before k_group writes perm). 4 x 32768 B.
    bf16*  wxlh    = (bf16*) (base + 600064 + 1024);
    bf16*  wxll    = (bf16*) (base + 600064 + 1024 + 32768);
    bf16*  wxrh    = (bf16*) (base + 600064 + 1024 + 65536);
    bf16*  wxrl    = (bf16*) (base + 600064 + 1024 + 98304);
    // range-partitioned (dst,payload) pairs: head of d_out (dead until k_agg).
    uint2* tmp2    = (uint2*)d_out;                           // 6.8 MB

    hipMemsetAsync(sum_ea, 0, 16, stream);

    const int NTILES = (NODES + 31) / 32;  // 1563

    k_wx      <<<384, 256, 0, stream>>>((const float*)d_in[2], (const float*)d_in[4],
                                        (const float*)d_in[11], (const float*)d_in[13],
                                        wxlh, wxll, wxrh, wxrl,
                                        w1t_hi, w1t_lo, w2t_hi, w2t_lo);
    k_fuse    <<<FUSE_GRID, 256, 0, stream>>>(edge_attr, edge_index, sum_ea, rhist,
                                              x, wxlh, wxll, wxrh, wxrl,
                                              (const float*)d_in[3], (const float*)d_in[5],
                                              xl, xr);
    k_rscan   <<<1, 256, 0, stream>>>(rhist, base_r, off);
    k_scatter <<<SB, 256, 0, stream>>>(edge_index, edge_attr, sum_ea, rhist, tmp2);
    k_group   <<<NRANGE, 1024, 0, stream>>>(tmp2, base_r, off, perm);
    k_agg     <<<3125, 256, 0, stream>>>((const unsigned int*)xl,
                                         (const unsigned int*)xr,
                                         perm, off,
                                         (const float*)d_in[6], (const float*)d_in[7],
                                         out);
    k_epi     <<<NTILES, 256, 0, stream>>>(out, x, (const float*)d_in[8],
                                           (const float*)d_in[9], (const float*)d_in[10],
                                           w1t_hi, w1t_lo, (const float*)d_in[12],
                                           w2t_hi, w2t_lo, (const float*)d_in[14],
                                           (const float*)d_in[15], (const float*)d_in[16],
                                           out);
}

// Round 13
// 342.087 us; speedup vs baseline: 1.1438x; 1.0228x over previous
//
#include <hip/hip_runtime.h>
#include <hip/hip_bf16.h>

#define NODES 50000
#define NEDGE 800000
#define ETOT  850000   /* NEDGE + NODES self loops */

#define NRANGE 49            /* ceil(NODES/1024) dst ranges */
#define SB 256               /* scatter/hist blocks */
#define ES ((ETOT + SB - 1) / SB)   /* 3321 edges per slice */

#define XF_TILES 1563        /* ceil(NODES/32) */
#define HIST_BLKS 256
#define FUSE_GRID (2 * HIST_BLKS + (XF_TILES - HIST_BLKS))  /* 1819 */

typedef __hip_bfloat16 bf16;
typedef __attribute__((ext_vector_type(8))) short bf16x8;
typedef __attribute__((ext_vector_type(4))) float f32x4;

__device__ __forceinline__ bf16 f2bf(float v) { return __float2bfloat16(v); }
__device__ __forceinline__ float bflo(unsigned int v) { return __uint_as_float(v << 16); }
__device__ __forceinline__ float bfhi(unsigned int v) { return __uint_as_float(v & 0xffff0000u); }

__device__ __forceinline__ unsigned int pack2(float a, float b) {
    bf16 x = f2bf(a), y = f2bf(b);
    unsigned short xs = *reinterpret_cast<unsigned short*>(&x);
    unsigned short ys = *reinterpret_cast<unsigned short*>(&y);
    return ((unsigned int)ys << 16) | (unsigned int)xs;
}

__device__ __forceinline__ unsigned short bfbits(float v) {
    bf16 x = f2bf(v);
    return *reinterpret_cast<unsigned short*>(&x);
}

// Dekker split: hi = bf16(v), lo = bf16(v - float(hi))
__device__ __forceinline__ void hilo(float v, unsigned short& h, unsigned short& l) {
    h = bfbits(v);
    float hv = __uint_as_float((unsigned int)h << 16);
    l = bfbits(v - hv);
}

// split 8 fp32 -> hi/lo bf16x8
__device__ __forceinline__ void split8(const float* v, bf16x8& hi, bf16x8& lo) {
    #pragma unroll
    for (int e = 0; e < 8; ++e) {
        unsigned short hb, lb;
        hilo(v[e], hb, lb);
        ((short*)&hi)[e] = (short)hb;
        ((short*)&lo)[e] = (short)lb;
    }
}

// ---------------------------------------------------------------------------
// k_wx: all weight transpose+split work in ONE launch. [identical to R8]
// ---------------------------------------------------------------------------
__global__ __launch_bounds__(256) void k_wx(const float* W_l, const float* W_r,
                                            const float* W1, const float* W2,
                                            bf16* wlh, bf16* wll,
                                            bf16* wrh, bf16* wrl,
                                            bf16* w1h, bf16* w1l,
                                            bf16* w2h, bf16* w2l) {
    int tid = blockIdx.x * blockDim.x + threadIdx.x;   // 98304 threads
    unsigned short h, l;
    if (tid < 32768) {
        int m = tid >> 14, t = tid & 16383;
        int c = t >> 7, k = t & 127;
        hilo((m ? W_r : W_l)[k * 128 + c], h, l);
        (m ? wrh : wlh)[t] = *(bf16*)&h;
        (m ? wrl : wll)[t] = *(bf16*)&l;
    } else if (tid < 65536) {
        int t = tid - 32768;
        int c = t >> 7, k = t & 127;
        hilo(W1[k * 256 + c], h, l);
        w1h[t] = *(bf16*)&h;
        w1l[t] = *(bf16*)&l;
    } else {
        int t = tid - 65536;
        int c = t >> 8, k = t & 255;
        hilo(W2[k * 128 + c], h, l);
        w2h[t] = *(bf16*)&h;
        w2l[t] = *(bf16*)&l;
    }
}

// ---------------------------------------------------------------------------
// k_fuse: [byte-identical to passing R8]
// ---------------------------------------------------------------------------
__global__ __launch_bounds__(256) void k_fuse(const float* edge_attr, const int* ei,
                                              float* sum_ea, int* rhist,
                                              const float* x,
                                              const bf16* wlh, const bf16* wll,
                                              const bf16* wrh, const bf16* wrl,
                                              const float* b_l, const float* b_r,
                                              bf16* xl, bf16* xr) {
    __shared__ __align__(16) float s_x[32][132];
    const int bid = blockIdx.x;
    int idx;
    bool isprep;
    if (bid < 2 * HIST_BLKS) { isprep = (bid & 1); idx = bid >> 1; }
    else { isprep = false; idx = HIST_BLKS + (bid - 2 * HIST_BLKS); }

    if (isprep) {
        int* hcnt = (int*)&s_x[0][0];
        const int t = threadIdx.x;
        if (t < 64) hcnt[t] = 0;
        __syncthreads();
        const int e0 = idx * ES;
        int e1 = e0 + ES; if (e1 > ETOT) e1 = ETOT;
        float local = 0.f;
        for (int e = e0 + t; e < e1; e += 256) {
            int dst = (e < NEDGE) ? ei[NEDGE + e] : (e - NEDGE);
            atomicAdd(&hcnt[dst >> 10], 1);
            if (e < NEDGE) local += edge_attr[e];
        }
        #pragma unroll
        for (int s = 1; s < 64; s <<= 1) local += __shfl_xor(local, s, 64);
        if ((t & 63) == 0) atomicAdd(sum_ea, local);
        __syncthreads();
        if (t < 64) rhist[idx * 64 + t] = hcnt[t];
        return;
    }

    const int tid = threadIdx.x;
    const int n0 = idx * 32;
    for (int it = 0; it < 4; ++it) {
        int idx4 = (it * 256 + tid) * 4;
        int n = idx4 >> 7, j = idx4 & 127;
        int node = n0 + n;
        float4 v = make_float4(0.f, 0.f, 0.f, 0.f);
        if (node < NODES) v = *(const float4*)(x + node * 128 + j);
        *(float4*)&s_x[n][j] = v;
    }
    __syncthreads();

    const int wv4  = tid >> 6;
    const int ln   = tid & 63;
    const int lrow = ln & 15;
    const int lk8  = (ln >> 4) << 3;
    const int m    = wv4 >> 1;
    const int cb   = (wv4 & 1) * 64;
    const bf16* Bh = m ? wrh : wlh;
    const bf16* Bl = m ? wrl : wll;
    const float* bias = m ? b_r : b_l;

    f32x4 acc[2][4];
    #pragma unroll
    for (int mt = 0; mt < 2; ++mt)
        #pragma unroll
        for (int i = 0; i < 4; ++i)
            acc[mt][i] = (f32x4){0.f, 0.f, 0.f, 0.f};
    #pragma unroll
    for (int kk = 0; kk < 4; ++kk) {
        int k0 = kk * 32 + lk8;
        float a0f[8], a1f[8];
        *(float4*)&a0f[0] = *(const float4*)&s_x[lrow][k0];
        *(float4*)&a0f[4] = *(const float4*)&s_x[lrow][k0 + 4];
        *(float4*)&a1f[0] = *(const float4*)&s_x[16 + lrow][k0];
        *(float4*)&a1f[4] = *(const float4*)&s_x[16 + lrow][k0 + 4];
        bf16x8 a0h, a0l, a1h, a1l;
        split8(a0f, a0h, a0l);
        split8(a1f, a1h, a1l);
        #pragma unroll
        for (int i = 0; i < 4; ++i) {
            int col = cb + (i << 4) + lrow;
            bf16x8 bh = *(const bf16x8*)(Bh + col * 128 + k0);
            bf16x8 bl = *(const bf16x8*)(Bl + col * 128 + k0);
            acc[0][i] = __builtin_amdgcn_mfma_f32_16x16x32_bf16(a0l, bh, acc[0][i], 0, 0, 0);
            acc[0][i] = __builtin_amdgcn_mfma_f32_16x16x32_bf16(a0h, bl, acc[0][i], 0, 0, 0);
            acc[0][i] = __builtin_amdgcn_mfma_f32_16x16x32_bf16(a0h, bh, acc[0][i], 0, 0, 0);
            acc[1][i] = __builtin_amdgcn_mfma_f32_16x16x32_bf16(a1l, bh, acc[1][i], 0, 0, 0);
            acc[1][i] = __builtin_amdgcn_mfma_f32_16x16x32_bf16(a1h, bl, acc[1][i], 0, 0, 0);
            acc[1][i] = __builtin_amdgcn_mfma_f32_16x16x32_bf16(a1h, bh, acc[1][i], 0, 0, 0);
        }
    }
    __syncthreads();
    bf16* s_o = (bf16*)&s_x[0][0];
    #pragma unroll
    for (int mt = 0; mt < 2; ++mt) {
        #pragma unroll
        for (int i = 0; i < 4; ++i) {
            int colg = cb + (i << 4) + lrow;
            float bv = bias[colg];
            #pragma unroll
            for (int r = 0; r < 4; ++r) {
                int row = (mt << 4) + ((ln >> 4) << 2) + r;
                s_o[row * 264 + m * 136 + colg] = f2bf(acc[mt][i][r] + bv);
            }
        }
    }
    __syncthreads();
    #pragma unroll
    for (int rep = 0; rep < 2; ++rep) {
        int idx2 = rep * 256 + tid;
        int row = idx2 >> 4, cc = (idx2 & 15) * 8;
        int node = n0 + row;
        if (node < NODES) {
            *(float4*)(xl + node * 128 + cc) = *(const float4*)(s_o + row * 264 + cc);
            *(float4*)(xr + node * 128 + cc) = *(const float4*)(s_o + row * 264 + 136 + cc);
        }
    }
}

// ---------------------------------------------------------------------------
// k_rscan / k_scatter / k_group: [byte-identical to passing R8]
// ---------------------------------------------------------------------------
__global__ __launch_bounds__(256) void k_rscan(int* rhist, int* base_r, int* off) {
    __shared__ int s_w[4];
    __shared__ int s_run;
    const int t = threadIdx.x, lane = t & 63, w = t >> 6;
    if (t == 0) s_run = 0;
    __syncthreads();
    for (int r = 0; r < NRANGE; ++r) {
        int v = rhist[t * 64 + r];
        int inc = v;
        #pragma unroll
        for (int d = 1; d < 64; d <<= 1) {
            int y = __shfl_up(inc, d, 64);
            if (lane >= d) inc += y;
        }
        if (lane == 63) s_w[w] = inc;
        __syncthreads();
        int woff = 0;
        #pragma unroll
        for (int ww = 0; ww < 4; ++ww) if (ww < w) woff += s_w[ww];
        int tot = s_w[0] + s_w[1] + s_w[2] + s_w[3];
        int runv = s_run;
        rhist[t * 64 + r] = runv + woff + (inc - v);
        if (t == 0) base_r[r] = runv;
        __syncthreads();
        if (t == 0) s_run = runv + tot;
        __syncthreads();
    }
    if (t == 0) { base_r[NRANGE] = ETOT; off[NODES] = ETOT; }
}

__global__ __launch_bounds__(256) void k_scatter(const int* ei, const float* edge_attr,
                                                 const float* sum_ea, const int* rhist,
                                                 uint2* tmp2) {
    __shared__ int cur[64];
    const int b = blockIdx.x, t = threadIdx.x;
    if (t < 64) cur[t] = rhist[b * 64 + t];
    __syncthreads();
    const float meanv = sum_ea[0] * (1.f / (float)NEDGE);
    const int e0 = b * ES;
    int e1 = e0 + ES; if (e1 > ETOT) e1 = ETOT;
    for (int e = e0 + t; e < e1; e += 256) {
        int src, dst; float eav;
        if (e < NEDGE) { src = ei[e]; dst = ei[NEDGE + e]; eav = edge_attr[e]; }
        else           { src = e - NEDGE; dst = src; eav = meanv; }
        int pos = atomicAdd(&cur[dst >> 10], 1);
        tmp2[pos] = make_uint2((unsigned int)dst,
                               ((unsigned int)bfbits(eav) << 16) | (unsigned int)src);
    }
}

__global__ __launch_bounds__(1024) void k_group(const uint2* tmp2, const int* base_r,
                                                int* off, unsigned int* perm) {
    __shared__ int lcnt[1024];
    __shared__ int s_w16[16];
    const int r = blockIdx.x, t = threadIdx.x;
    const int lane = t & 63, w = t >> 6;
    const int n0 = r << 10;
    const int s0 = base_r[r], s1 = base_r[r + 1];
    lcnt[t] = 0;
    __syncthreads();
    for (int i = s0 + t; i < s1; i += 1024) {
        int d = (int)tmp2[i].x;
        atomicAdd(&lcnt[d - n0], 1);
    }
    __syncthreads();
    int v = lcnt[t];
    int inc = v;
    #pragma unroll
    for (int d = 1; d < 64; d <<= 1) {
        int y = __shfl_up(inc, d, 64);
        if (lane >= d) inc += y;
    }
    if (lane == 63) s_w16[w] = inc;
    __syncthreads();
    int woff = 0;
    #pragma unroll
    for (int ww = 0; ww < 16; ++ww) if (ww < w) woff += s_w16[ww];
    int pos0 = s0 + woff + (inc - v);
    lcnt[t] = pos0;
    if (n0 + t < NODES) off[n0 + t] = pos0;
    __syncthreads();
    for (int i = s0 + t; i < s1; i += 1024) {
        uint2 p = tmp2[i];
        int pos = atomicAdd(&lcnt[(int)p.x - n0], 1);
        perm[pos] = p.y;
    }
}

// ---------------------------------------------------------------------------
// k_agg: [byte-identical to passing R10]
// ---------------------------------------------------------------------------
__global__ __launch_bounds__(256) void k_agg(const unsigned int* xl32,
                                             const unsigned int* xr32,
                                             const unsigned int* perm, const int* off,
                                             const float* W_e, const float* att,
                                             float* outp) {
    const int lane = threadIdx.x & 63;
    const int wave0 = blockIdx.x * 4 + (threadIdx.x >> 6);
    const int nwaves = gridDim.x * 4;
    const int c = 2 * lane;
    const float we1 = W_e[c], we2 = W_e[c + 1];
    const float a1 = att[c], a2 = att[c + 1];
    for (int n = wave0; n < NODES; n += nwaves) {
        unsigned int xru = xr32[n * 64 + lane];
        float xr1 = bflo(xru), xr2 = bfhi(xru);
        int s0 = off[n], s1 = off[n + 1];
        float m = -1e30f, l = 0.f, acc1 = 0.f, acc2 = 0.f;
        int j = s0;
        for (; j + 4 <= s1; j += 4) {
            unsigned int u0 = perm[j];
            unsigned int u1 = perm[j + 1];
            unsigned int u2 = perm[j + 2];
            unsigned int u3 = perm[j + 3];
            unsigned int g0 = xl32[(u0 & 0xffffu) * 64 + lane];
            unsigned int g1 = xl32[(u1 & 0xffffu) * 64 + lane];
            unsigned int g2 = xl32[(u2 & 0xffffu) * 64 + lane];
            unsigned int g3 = xl32[(u3 & 0xffffu) * 64 + lane];
            float e0 = bfhi(u0), e1 = bfhi(u1), e2 = bfhi(u2), e3 = bfhi(u3);
            float x01 = bflo(g0), x02 = bfhi(g0);
            float x11 = bflo(g1), x12 = bfhi(g1);
            float x21 = bflo(g2), x22 = bfhi(g2);
            float x31 = bflo(g3), x32 = bfhi(g3);
            float p0, p1, p2, p3;
            {
                float v1 = x01 + xr1 + e0 * we1, v2 = x02 + xr2 + e0 * we2;
                v1 = (v1 > 0.f) ? v1 : 0.2f * v1;
                v2 = (v2 > 0.f) ? v2 : 0.2f * v2;
                p0 = v1 * a1 + v2 * a2;
            }
            {
                float v1 = x11 + xr1 + e1 * we1, v2 = x12 + xr2 + e1 * we2;
                v1 = (v1 > 0.f) ? v1 : 0.2f * v1;
                v2 = (v2 > 0.f) ? v2 : 0.2f * v2;
                p1 = v1 * a1 + v2 * a2;
            }
            {
                float v1 = x21 + xr1 + e2 * we1, v2 = x22 + xr2 + e2 * we2;
                v1 = (v1 > 0.f) ? v1 : 0.2f * v1;
                v2 = (v2 > 0.f) ? v2 : 0.2f * v2;
                p2 = v1 * a1 + v2 * a2;
            }
            {
                float v1 = x31 + xr1 + e3 * we1, v2 = x32 + xr2 + e3 * we2;
                v1 = (v1 > 0.f) ? v1 : 0.2f * v1;
                v2 = (v2 > 0.f) ? v2 : 0.2f * v2;
                p3 = v1 * a1 + v2 * a2;
            }
            p0 += __shfl_xor(p0, 1, 64); p1 += __shfl_xor(p1, 1, 64);
            p2 += __shfl_xor(p2, 1, 64); p3 += __shfl_xor(p3, 1, 64);
            p0 += __shfl_xor(p0, 2, 64); p1 += __shfl_xor(p1, 2, 64);
            p2 += __shfl_xor(p2, 2, 64); p3 += __shfl_xor(p3, 2, 64);
            p0 += __shfl_xor(p0, 4, 64); p1 += __shfl_xor(p1, 4, 64);
            p2 += __shfl_xor(p2, 4, 64); p3 += __shfl_xor(p3, 4, 64);
            p0 += __shfl_xor(p0, 8, 64); p1 += __shfl_xor(p1, 8, 64);
            p2 += __shfl_xor(p2, 8, 64); p3 += __shfl_xor(p3, 8, 64);
            float nm = fmaxf(fmaxf(m, fmaxf(p0, p1)), fmaxf(p2, p3));
            float sc = __expf(m - nm);
            float E0 = __expf(p0 - nm);
            float E1 = __expf(p1 - nm);
            float E2 = __expf(p2 - nm);
            float E3 = __expf(p3 - nm);
            l = l * sc + E0 + E1 + E2 + E3;
            acc1 = acc1 * sc + E0 * x01 + E1 * x11 + E2 * x21 + E3 * x31;
            acc2 = acc2 * sc + E0 * x02 + E1 * x12 + E2 * x22 + E3 * x32;
            m = nm;
        }
        for (; j < s1; ++j) {
            unsigned int u0 = perm[j];
            unsigned int g0 = xl32[(u0 & 0xffffu) * 64 + lane];
            float e0 = bfhi(u0);
            float x01 = bflo(g0), x02 = bfhi(g0);
            float v1 = x01 + xr1 + e0 * we1, v2 = x02 + xr2 + e0 * we2;
            v1 = (v1 > 0.f) ? v1 : 0.2f * v1;
            v2 = (v2 > 0.f) ? v2 : 0.2f * v2;
            float p = v1 * a1 + v2 * a2;
            p += __shfl_xor(p, 1, 64);
            p += __shfl_xor(p, 2, 64);
            p += __shfl_xor(p, 4, 64);
            p += __shfl_xor(p, 8, 64);
            float nm = fmaxf(m, p);
            float sc = __expf(m - nm);
            float ee = __expf(p - nm);
            l = l * sc + ee;
            acc1 = acc1 * sc + ee * x01;
            acc2 = acc2 * sc + ee * x02;
            m = nm;
        }
        float inv = 1.f / fmaxf(l, 1e-30f);
        *(float2*)(outp + n * 128 + c) = make_float2(acc1 * inv, acc2 * inv);
    }
}

// ---------------------------------------------------------------------------
// k_epi v6: 512 threads / 8 waves, M=32 kept. Same per-block work, weight
// traffic, and barrier count as the 76us R7 kernel — but 2x waves per block
// (24 waves/CU at 3 blocks/CU) to fill the ~70% latency stall the counters
// show. FFN1 per-wave N=32 (2 col-tiles), FFN2 per-wave N=16 (1 col-tile).
// Fused elu+gate+y phase: each wave owns 4 nodes. LN: 16 threads/node.
// ---------------------------------------------------------------------------
__global__ __launch_bounds__(512) void k_epi(const float* out_agg, const float* x,
                                             const float* bias_out,
                                             const float* W_gate, const float* b_gate,
                                             const bf16* w1h, const bf16* w1l,
                                             const float* b_ffn1,
                                             const bf16* w2h, const bf16* w2l,
                                             const float* b_ffn2,
                                             const float* gamma, const float* beta,
                                             float* out) {
    __shared__ __align__(16) float s_y[32][132];   // y, then z (fp32)
    __shared__ __align__(16) float s_t[32][260];   // relu(ffn1) fp32 (FFN2 A)
    __shared__ float s_mu[32], s_rs[32];
    const int tid = threadIdx.x;
    const int lane = tid & 63;
    const int wvi  = tid >> 6;          // wave 0..7
    const int n0 = blockIdx.x * 32;
    int nn = NODES - n0; if (nn > 32) nn = 32;

    // ---- fused elu+gate+y: wave wvi owns nodes wvi*4..wvi*4+3 ----
    {
        const int c = 2 * lane;
        const float bo1 = bias_out[c],  bo2 = bias_out[c + 1];
        const float wg1 = W_gate[c],    wg2 = W_gate[c + 1];
        const float bg0 = b_gate[0];
        for (int s = 0; s < 4; ++s) {
            const int nl = wvi * 4 + s;
            const int n = n0 + nl;
            if (n < NODES) {
                float2 v = *(const float2*)(out_agg + n * 128 + c);
                float h1 = v.x + bo1, h2 = v.y + bo2;
                h1 = (h1 > 0.f) ? h1 : (__expf(h1) - 1.f);
                h2 = (h2 > 0.f) ? h2 : (__expf(h2) - 1.f);
                float g = h1 * wg1 + h2 * wg2;
                g += __shfl_xor(g, 1, 64);
                g += __shfl_xor(g, 2, 64);
                g += __shfl_xor(g, 4, 64);
                g += __shfl_xor(g, 8, 64);
                g += __shfl_xor(g, 16, 64);
                g += __shfl_xor(g, 32, 64);
                g = 1.f / (1.f + __expf(-(g + bg0)));
                float2 xv = *(const float2*)(x + n * 128 + c);
                float y1 = g * h1 + (1.f - g) * xv.x;
                float y2 = g * h2 + (1.f - g) * xv.y;
                *(float2*)&s_y[nl][c] = make_float2(y1, y2);
            } else {
                *(float2*)&s_y[nl][c] = make_float2(0.f, 0.f);
            }
        }
    }
    __syncthreads();

    const int wv   = wvi;
    const int ln   = lane;
    const int lrow = ln & 15;           // A row / B,D col within tile
    const int lk8  = (ln >> 4) << 3;    // k chunk base: 0,8,16,24

    // FFN1: t = relu(y @ W1 + b1). M=32 (2 tiles), per-wave N=32 (2 tiles), K=128.
    f32x4 acc1[2][2];
    #pragma unroll
    for (int mt = 0; mt < 2; ++mt)
        #pragma unroll
        for (int i = 0; i < 2; ++i)
            acc1[mt][i] = (f32x4){0.f, 0.f, 0.f, 0.f};
    #pragma unroll
    for (int kk = 0; kk < 4; ++kk) {
        int k0 = kk * 32 + lk8;
        float a0f[8], a1f[8];
        *(float4*)&a0f[0] = *(const float4*)&s_y[lrow][k0];
        *(float4*)&a0f[4] = *(const float4*)&s_y[lrow][k0 + 4];
        *(float4*)&a1f[0] = *(const float4*)&s_y[16 + lrow][k0];
        *(float4*)&a1f[4] = *(const float4*)&s_y[16 + lrow][k0 + 4];
        bf16x8 a0h, a0l, a1h, a1l;
        split8(a0f, a0h, a0l);
        split8(a1f, a1h, a1l);
        #pragma unroll
        for (int i = 0; i < 2; ++i) {
            int col = (wv << 5) + (i << 4) + lrow;
            bf16x8 bh = *(const bf16x8*)(w1h + col * 128 + k0);
            bf16x8 bl = *(const bf16x8*)(w1l + col * 128 + k0);
            acc1[0][i] = __builtin_amdgcn_mfma_f32_16x16x32_bf16(a0l, bh, acc1[0][i], 0, 0, 0);
            acc1[0][i] = __builtin_amdgcn_mfma_f32_16x16x32_bf16(a0h, bl, acc1[0][i], 0, 0, 0);
            acc1[0][i] = __builtin_amdgcn_mfma_f32_16x16x32_bf16(a0h, bh, acc1[0][i], 0, 0, 0);
            acc1[1][i] = __builtin_amdgcn_mfma_f32_16x16x32_bf16(a1l, bh, acc1[1][i], 0, 0, 0);
            acc1[1][i] = __builtin_amdgcn_mfma_f32_16x16x32_bf16(a1h, bl, acc1[1][i], 0, 0, 0);
            acc1[1][i] = __builtin_amdgcn_mfma_f32_16x16x32_bf16(a1h, bh, acc1[1][i], 0, 0, 0);
        }
    }
    // epilogue: +b1, relu -> s_t (fp32)
    #pragma unroll
    for (int mt = 0; mt < 2; ++mt) {
        #pragma unroll
        for (int i = 0; i < 2; ++i) {
            int col = (wv << 5) + (i << 4) + lrow;
            float bv = b_ffn1[col];
            #pragma unroll
            for (int r = 0; r < 4; ++r) {
                int row = (mt << 4) + ((ln >> 4) << 2) + r;
                s_t[row][col] = fmaxf(acc1[mt][i][r] + bv, 0.f);
            }
        }
    }
    __syncthreads();

    // FFN2: ffn = t @ W2 + b2. M=32 (2 tiles), per-wave N=16 (1 tile), K=256.
    f32x4 acc2[2];
    acc2[0] = (f32x4){0.f, 0.f, 0.f, 0.f};
    acc2[1] = (f32x4){0.f, 0.f, 0.f, 0.f};
    #pragma unroll
    for (int kk = 0; kk < 8; ++kk) {
        int k0 = kk * 32 + lk8;
        float a0f[8], a1f[8];
        *(float4*)&a0f[0] = *(const float4*)&s_t[lrow][k0];
        *(float4*)&a0f[4] = *(const float4*)&s_t[lrow][k0 + 4];
        *(float4*)&a1f[0] = *(const float4*)&s_t[16 + lrow][k0];
        *(float4*)&a1f[4] = *(const float4*)&s_t[16 + lrow][k0 + 4];
        bf16x8 a0h, a0l, a1h, a1l;
        split8(a0f, a0h, a0l);
        split8(a1f, a1h, a1l);
        int col = (wv << 4) + lrow;
        bf16x8 bh = *(const bf16x8*)(w2h + col * 256 + k0);
        bf16x8 bl = *(const bf16x8*)(w2l + col * 256 + k0);
        acc2[0] = __builtin_amdgcn_mfma_f32_16x16x32_bf16(a0l, bh, acc2[0], 0, 0, 0);
        acc2[0] = __builtin_amdgcn_mfma_f32_16x16x32_bf16(a0h, bl, acc2[0], 0, 0, 0);
        acc2[0] = __builtin_amdgcn_mfma_f32_16x16x32_bf16(a0h, bh, acc2[0], 0, 0, 0);
        acc2[1] = __builtin_amdgcn_mfma_f32_16x16x32_bf16(a1l, bh, acc2[1], 0, 0, 0);
        acc2[1] = __builtin_amdgcn_mfma_f32_16x16x32_bf16(a1h, bl, acc2[1], 0, 0, 0);
        acc2[1] = __builtin_amdgcn_mfma_f32_16x16x32_bf16(a1h, bh, acc2[1], 0, 0, 0);
    }
    // epilogue: y += ffn + b2  (disjoint (row,col) per lane across block)
    {
        int col = (wv << 4) + lrow;
        float bv = b_ffn2[col];
        #pragma unroll
        for (int mt = 0; mt < 2; ++mt) {
            #pragma unroll
            for (int r = 0; r < 4; ++r) {
                int row = (mt << 4) + ((ln >> 4) << 2) + r;
                s_y[row][col] += acc2[mt][r] + bv;
            }
        }
    }
    __syncthreads();
    // LayerNorm stats: 16 threads per node (512 threads, 32 nodes)
    {
        int n = tid >> 4, kb = (tid & 15) * 8;
        float4 v0 = *(const float4*)&s_y[n][kb];
        float4 v1 = *(const float4*)&s_y[n][kb + 4];
        float s  = v0.x + v0.y + v0.z + v0.w + v1.x + v1.y + v1.z + v1.w;
        float ss = v0.x * v0.x + v0.y * v0.y + v0.z * v0.z + v0.w * v0.w
                 + v1.x * v1.x + v1.y * v1.y + v1.z * v1.z + v1.w * v1.w;
        s  += __shfl_xor(s, 1, 64);  ss += __shfl_xor(ss, 1, 64);
        s  += __shfl_xor(s, 2, 64);  ss += __shfl_xor(ss, 2, 64);
        s  += __shfl_xor(s, 4, 64);  ss += __shfl_xor(ss, 4, 64);
        s  += __shfl_xor(s, 8, 64);  ss += __shfl_xor(ss, 8, 64);
        if ((tid & 15) == 0) {
            float mu = s * (1.f / 128.f);
            float var = ss * (1.f / 128.f) - mu * mu;
            s_mu[n] = mu;
            s_rs[n] = rsqrtf(fmaxf(var, 0.f) + 1e-5f);
        }
    }
    __syncthreads();
    // normalize + store (fp32): 4096 floats, 512 threads x float4 x 2 iters
    for (int it = 0; it < 2; ++it) {
        int idx4 = (it * 512 + tid) * 4;
        int n = idx4 >> 7, j = idx4 & 127;
        if (n < nn) {
            float mu = s_mu[n], rs = s_rs[n];
            float4 gv = *(const float4*)(gamma + j);
            float4 bv = *(const float4*)(beta + j);
            float4 v = *(const float4*)&s_y[n][j];
            float4 o;
            o.x = (v.x - mu) * rs * gv.x + bv.x;
            o.y = (v.y - mu) * rs * gv.y + bv.y;
            o.z = (v.z - mu) * rs * gv.z + bv.z;
            o.w = (v.w - mu) * rs * gv.w + bv.w;
            *(float4*)(out + (n0 + n) * 128 + j) = o;
        }
    }
}

// ---------------------------------------------------------------------------
extern "C" void kernel_launch(void* const* d_in, const int* in_sizes, int n_in,
                              void* d_out, int out_size, void* d_ws, size_t ws_size,
                              hipStream_t stream) {
    const float* x         = (const float*)d_in[0];
    const float* edge_attr = (const float*)d_in[1];
    const int* edge_index  = (const int*)d_in[17];
    float* out = (float*)d_out;

    char* base = (char*)d_ws;
    // workspace layout (29,600,064 B total, hardware-proven extents):
    float* sum_ea  = (float*)(base + 16);                     // 16 B
    int*   rhist   = (int*)  (base + 32);                     // 65536
    bf16*  w1t_hi  = (bf16*) (base + 32 + 65536);             // 65536 (disjoint from rhist)
    bf16*  w1t_lo  = (bf16*) (base + 32 + 131072);            // 65536 -> ends 196640 < 200032
    int*   off     = (int*)  (base + 200032);                 // 200004 (+pad)
    int*   base_r  = (int*)  (base + 400064);                 // 50 ints (pad to 256)
    bf16*  w2t_hi  = (bf16*) (base + 400064 + 256);           // 65536 (disjoint from base_r)
    bf16*  w2t_lo  = (bf16*) (base + 400064 + 256 + 65536);   // ends 531392 < 600064
    unsigned int* perm = (unsigned int*)(base + 600064);      // 3400000
    bf16*  xl      = (bf16*) (base + 4000064);                // 12800000
    bf16*  xr      = (bf16*) (base + 16800064);               // 12800000
    // xform weight split pairs: perm head +1024 (consumed by k_fuse, dead
    // before k_group writes perm). 4 x 32768 B.
    bf16*  wxlh    = (bf16*) (base + 600064 + 1024);
    bf16*  wxll    = (bf16*) (base + 600064 + 1024 + 32768);
    bf16*  wxrh    = (bf16*) (base + 600064 + 1024 + 65536);
    bf16*  wxrl    = (bf16*) (base + 600064 + 1024 + 98304);
    // range-partitioned (dst,payload) pairs: head of d_out (dead until k_agg).
    uint2* tmp2    = (uint2*)d_out;                           // 6.8 MB

    hipMemsetAsync(sum_ea, 0, 16, stream);

    const int NTILES = (NODES + 31) / 32;  // 1563

    k_wx      <<<384, 256, 0, stream>>>((const float*)d_in[2], (const float*)d_in[4],
                                        (const float*)d_in[11], (const float*)d_in[13],
                                        wxlh, wxll, wxrh, wxrl,
                                        w1t_hi, w1t_lo, w2t_hi, w2t_lo);
    k_fuse    <<<FUSE_GRID, 256, 0, stream>>>(edge_attr, edge_index, sum_ea, rhist,
                                              x, wxlh, wxll, wxrh, wxrl,
                                              (const float*)d_in[3], (const float*)d_in[5],
                                              xl, xr);
    k_rscan   <<<1, 256, 0, stream>>>(rhist, base_r, off);
    k_scatter <<<SB, 256, 0, stream>>>(edge_index, edge_attr, sum_ea, rhist, tmp2);
    k_group   <<<NRANGE, 1024, 0, stream>>>(tmp2, base_r, off, perm);
    k_agg     <<<3125, 256, 0, stream>>>((const unsigned int*)xl,
                                         (const unsigned int*)xr,
                                         perm, off,
                                         (const float*)d_in[6], (const float*)d_in[7],
                                         out);
    k_epi     <<<NTILES, 512, 0, stream>>>(out, x, (const float*)d_in[8],
                                           (const float*)d_in[9], (const float*)d_in[10],
                                           w1t_hi, w1t_lo, (const float*)d_in[12],
                                           w2t_hi, w2t_lo, (const float*)d_in[14],
                                           (const float*)d_in[15], (const float*)d_in[16],
                                           out);
}

// Round 16
// 340.700 us; speedup vs baseline: 1.1484x; 1.0041x over previous
//
#include <hip/hip_runtime.h>
#include <hip/hip_bf16.h>

#define NODES 50000
#define NEDGE 800000
#define ETOT  850000   /* NEDGE + NODES self loops */

#define NRANGE 49            /* ceil(NODES/1024) dst ranges */
#define SB 256               /* scatter/hist blocks */
#define ES ((ETOT + SB - 1) / SB)   /* 3321 edges per slice */

#define XF_TILES 1563        /* ceil(NODES/32) */
#define HIST_BLKS 256
#define FUSE_GRID (2 * HIST_BLKS + (XF_TILES - HIST_BLKS))  /* 1819 */

typedef __hip_bfloat16 bf16;
typedef __attribute__((ext_vector_type(8))) short bf16x8;
typedef __attribute__((ext_vector_type(4))) float f32x4;

__device__ __forceinline__ bf16 f2bf(float v) { return __float2bfloat16(v); }
__device__ __forceinline__ float bflo(unsigned int v) { return __uint_as_float(v << 16); }
__device__ __forceinline__ float bfhi(unsigned int v) { return __uint_as_float(v & 0xffff0000u); }

__device__ __forceinline__ unsigned int pack2(float a, float b) {
    bf16 x = f2bf(a), y = f2bf(b);
    unsigned short xs = *reinterpret_cast<unsigned short*>(&x);
    unsigned short ys = *reinterpret_cast<unsigned short*>(&y);
    return ((unsigned int)ys << 16) | (unsigned int)xs;
}

__device__ __forceinline__ unsigned short bfbits(float v) {
    bf16 x = f2bf(v);
    return *reinterpret_cast<unsigned short*>(&x);
}

// Dekker split: hi = bf16(v), lo = bf16(v - float(hi))
__device__ __forceinline__ void hilo(float v, unsigned short& h, unsigned short& l) {
    h = bfbits(v);
    float hv = __uint_as_float((unsigned int)h << 16);
    l = bfbits(v - hv);
}

// split 8 fp32 -> hi/lo bf16x8 (used by k_fuse xform role)
__device__ __forceinline__ void split8(const float* v, bf16x8& hi, bf16x8& lo) {
    #pragma unroll
    for (int e = 0; e < 8; ++e) {
        unsigned short hb, lb;
        hilo(v[e], hb, lb);
        ((short*)&hi)[e] = (short)hb;
        ((short*)&lo)[e] = (short)lb;
    }
}

// ---------------------------------------------------------------------------
// k_wx: all weight transpose+split work in ONE launch. [identical to R8]
// ---------------------------------------------------------------------------
__global__ __launch_bounds__(256) void k_wx(const float* W_l, const float* W_r,
                                            const float* W1, const float* W2,
                                            bf16* wlh, bf16* wll,
                                            bf16* wrh, bf16* wrl,
                                            bf16* w1h, bf16* w1l,
                                            bf16* w2h, bf16* w2l) {
    int tid = blockIdx.x * blockDim.x + threadIdx.x;   // 98304 threads
    unsigned short h, l;
    if (tid < 32768) {
        int m = tid >> 14, t = tid & 16383;
        int c = t >> 7, k = t & 127;
        hilo((m ? W_r : W_l)[k * 128 + c], h, l);
        (m ? wrh : wlh)[t] = *(bf16*)&h;
        (m ? wrl : wll)[t] = *(bf16*)&l;
    } else if (tid < 65536) {
        int t = tid - 32768;
        int c = t >> 7, k = t & 127;
        hilo(W1[k * 256 + c], h, l);
        w1h[t] = *(bf16*)&h;
        w1l[t] = *(bf16*)&l;
    } else {
        int t = tid - 65536;
        int c = t >> 8, k = t & 255;
        hilo(W2[k * 128 + c], h, l);
        w2h[t] = *(bf16*)&h;
        w2l[t] = *(bf16*)&l;
    }
}

// ---------------------------------------------------------------------------
// k_fuse: [byte-identical to passing R8]
// ---------------------------------------------------------------------------
__global__ __launch_bounds__(256) void k_fuse(const float* edge_attr, const int* ei,
                                              float* sum_ea, int* rhist,
                                              const float* x,
                                              const bf16* wlh, const bf16* wll,
                                              const bf16* wrh, const bf16* wrl,
                                              const float* b_l, const float* b_r,
                                              bf16* xl, bf16* xr) {
    __shared__ __align__(16) float s_x[32][132];
    const int bid = blockIdx.x;
    int idx;
    bool isprep;
    if (bid < 2 * HIST_BLKS) { isprep = (bid & 1); idx = bid >> 1; }
    else { isprep = false; idx = HIST_BLKS + (bid - 2 * HIST_BLKS); }

    if (isprep) {
        int* hcnt = (int*)&s_x[0][0];
        const int t = threadIdx.x;
        if (t < 64) hcnt[t] = 0;
        __syncthreads();
        const int e0 = idx * ES;
        int e1 = e0 + ES; if (e1 > ETOT) e1 = ETOT;
        float local = 0.f;
        for (int e = e0 + t; e < e1; e += 256) {
            int dst = (e < NEDGE) ? ei[NEDGE + e] : (e - NEDGE);
            atomicAdd(&hcnt[dst >> 10], 1);
            if (e < NEDGE) local += edge_attr[e];
        }
        #pragma unroll
        for (int s = 1; s < 64; s <<= 1) local += __shfl_xor(local, s, 64);
        if ((t & 63) == 0) atomicAdd(sum_ea, local);
        __syncthreads();
        if (t < 64) rhist[idx * 64 + t] = hcnt[t];
        return;
    }

    const int tid = threadIdx.x;
    const int n0 = idx * 32;
    for (int it = 0; it < 4; ++it) {
        int idx4 = (it * 256 + tid) * 4;
        int n = idx4 >> 7, j = idx4 & 127;
        int node = n0 + n;
        float4 v = make_float4(0.f, 0.f, 0.f, 0.f);
        if (node < NODES) v = *(const float4*)(x + node * 128 + j);
        *(float4*)&s_x[n][j] = v;
    }
    __syncthreads();

    const int wv4  = tid >> 6;
    const int ln   = tid & 63;
    const int lrow = ln & 15;
    const int lk8  = (ln >> 4) << 3;
    const int m    = wv4 >> 1;
    const int cb   = (wv4 & 1) * 64;
    const bf16* Bh = m ? wrh : wlh;
    const bf16* Bl = m ? wrl : wll;
    const float* bias = m ? b_r : b_l;

    f32x4 acc[2][4];
    #pragma unroll
    for (int mt = 0; mt < 2; ++mt)
        #pragma unroll
        for (int i = 0; i < 4; ++i)
            acc[mt][i] = (f32x4){0.f, 0.f, 0.f, 0.f};
    #pragma unroll
    for (int kk = 0; kk < 4; ++kk) {
        int k0 = kk * 32 + lk8;
        float a0f[8], a1f[8];
        *(float4*)&a0f[0] = *(const float4*)&s_x[lrow][k0];
        *(float4*)&a0f[4] = *(const float4*)&s_x[lrow][k0 + 4];
        *(float4*)&a1f[0] = *(const float4*)&s_x[16 + lrow][k0];
        *(float4*)&a1f[4] = *(const float4*)&s_x[16 + lrow][k0 + 4];
        bf16x8 a0h, a0l, a1h, a1l;
        split8(a0f, a0h, a0l);
        split8(a1f, a1h, a1l);
        #pragma unroll
        for (int i = 0; i < 4; ++i) {
            int col = cb + (i << 4) + lrow;
            bf16x8 bh = *(const bf16x8*)(Bh + col * 128 + k0);
            bf16x8 bl = *(const bf16x8*)(Bl + col * 128 + k0);
            acc[0][i] = __builtin_amdgcn_mfma_f32_16x16x32_bf16(a0l, bh, acc[0][i], 0, 0, 0);
            acc[0][i] = __builtin_amdgcn_mfma_f32_16x16x32_bf16(a0h, bl, acc[0][i], 0, 0, 0);
            acc[0][i] = __builtin_amdgcn_mfma_f32_16x16x32_bf16(a0h, bh, acc[0][i], 0, 0, 0);
            acc[1][i] = __builtin_amdgcn_mfma_f32_16x16x32_bf16(a1l, bh, acc[1][i], 0, 0, 0);
            acc[1][i] = __builtin_amdgcn_mfma_f32_16x16x32_bf16(a1h, bl, acc[1][i], 0, 0, 0);
            acc[1][i] = __builtin_amdgcn_mfma_f32_16x16x32_bf16(a1h, bh, acc[1][i], 0, 0, 0);
        }
    }
    __syncthreads();
    bf16* s_o = (bf16*)&s_x[0][0];
    #pragma unroll
    for (int mt = 0; mt < 2; ++mt) {
        #pragma unroll
        for (int i = 0; i < 4; ++i) {
            int colg = cb + (i << 4) + lrow;
            float bv = bias[colg];
            #pragma unroll
            for (int r = 0; r < 4; ++r) {
                int row = (mt << 4) + ((ln >> 4) << 2) + r;
                s_o[row * 264 + m * 136 + colg] = f2bf(acc[mt][i][r] + bv);
            }
        }
    }
    __syncthreads();
    #pragma unroll
    for (int rep = 0; rep < 2; ++rep) {
        int idx2 = rep * 256 + tid;
        int row = idx2 >> 4, cc = (idx2 & 15) * 8;
        int node = n0 + row;
        if (node < NODES) {
            *(float4*)(xl + node * 128 + cc) = *(const float4*)(s_o + row * 264 + cc);
            *(float4*)(xr + node * 128 + cc) = *(const float4*)(s_o + row * 264 + 136 + cc);
        }
    }
}

// ---------------------------------------------------------------------------
// k_rscan / k_scatter / k_group: [byte-identical to passing R8]
// ---------------------------------------------------------------------------
__global__ __launch_bounds__(256) void k_rscan(int* rhist, int* base_r, int* off) {
    __shared__ int s_w[4];
    __shared__ int s_run;
    const int t = threadIdx.x, lane = t & 63, w = t >> 6;
    if (t == 0) s_run = 0;
    __syncthreads();
    for (int r = 0; r < NRANGE; ++r) {
        int v = rhist[t * 64 + r];
        int inc = v;
        #pragma unroll
        for (int d = 1; d < 64; d <<= 1) {
            int y = __shfl_up(inc, d, 64);
            if (lane >= d) inc += y;
        }
        if (lane == 63) s_w[w] = inc;
        __syncthreads();
        int woff = 0;
        #pragma unroll
        for (int ww = 0; ww < 4; ++ww) if (ww < w) woff += s_w[ww];
        int tot = s_w[0] + s_w[1] + s_w[2] + s_w[3];
        int runv = s_run;
        rhist[t * 64 + r] = runv + woff + (inc - v);
        if (t == 0) base_r[r] = runv;
        __syncthreads();
        if (t == 0) s_run = runv + tot;
        __syncthreads();
    }
    if (t == 0) { base_r[NRANGE] = ETOT; off[NODES] = ETOT; }
}

__global__ __launch_bounds__(256) void k_scatter(const int* ei, const float* edge_attr,
                                                 const float* sum_ea, const int* rhist,
                                                 uint2* tmp2) {
    __shared__ int cur[64];
    const int b = blockIdx.x, t = threadIdx.x;
    if (t < 64) cur[t] = rhist[b * 64 + t];
    __syncthreads();
    const float meanv = sum_ea[0] * (1.f / (float)NEDGE);
    const int e0 = b * ES;
    int e1 = e0 + ES; if (e1 > ETOT) e1 = ETOT;
    for (int e = e0 + t; e < e1; e += 256) {
        int src, dst; float eav;
        if (e < NEDGE) { src = ei[e]; dst = ei[NEDGE + e]; eav = edge_attr[e]; }
        else           { src = e - NEDGE; dst = src; eav = meanv; }
        int pos = atomicAdd(&cur[dst >> 10], 1);
        tmp2[pos] = make_uint2((unsigned int)dst,
                               ((unsigned int)bfbits(eav) << 16) | (unsigned int)src);
    }
}

__global__ __launch_bounds__(1024) void k_group(const uint2* tmp2, const int* base_r,
                                                int* off, unsigned int* perm) {
    __shared__ int lcnt[1024];
    __shared__ int s_w16[16];
    const int r = blockIdx.x, t = threadIdx.x;
    const int lane = t & 63, w = t >> 6;
    const int n0 = r << 10;
    const int s0 = base_r[r], s1 = base_r[r + 1];
    lcnt[t] = 0;
    __syncthreads();
    for (int i = s0 + t; i < s1; i += 1024) {
        int d = (int)tmp2[i].x;
        atomicAdd(&lcnt[d - n0], 1);
    }
    __syncthreads();
    int v = lcnt[t];
    int inc = v;
    #pragma unroll
    for (int d = 1; d < 64; d <<= 1) {
        int y = __shfl_up(inc, d, 64);
        if (lane >= d) inc += y;
    }
    if (lane == 63) s_w16[w] = inc;
    __syncthreads();
    int woff = 0;
    #pragma unroll
    for (int ww = 0; ww < 16; ++ww) if (ww < w) woff += s_w16[ww];
    int pos0 = s0 + woff + (inc - v);
    lcnt[t] = pos0;
    if (n0 + t < NODES) off[n0 + t] = pos0;
    __syncthreads();
    for (int i = s0 + t; i < s1; i += 1024) {
        uint2 p = tmp2[i];
        int pos = atomicAdd(&lcnt[(int)p.x - n0], 1);
        perm[pos] = p.y;
    }
}

// ---------------------------------------------------------------------------
// k_agg: [byte-identical to passing R10]
// ---------------------------------------------------------------------------
__global__ __launch_bounds__(256) void k_agg(const unsigned int* xl32,
                                             const unsigned int* xr32,
                                             const unsigned int* perm, const int* off,
                                             const float* W_e, const float* att,
                                             float* outp) {
    const int lane = threadIdx.x & 63;
    const int wave0 = blockIdx.x * 4 + (threadIdx.x >> 6);
    const int nwaves = gridDim.x * 4;
    const int c = 2 * lane;
    const float we1 = W_e[c], we2 = W_e[c + 1];
    const float a1 = att[c], a2 = att[c + 1];
    for (int n = wave0; n < NODES; n += nwaves) {
        unsigned int xru = xr32[n * 64 + lane];
        float xr1 = bflo(xru), xr2 = bfhi(xru);
        int s0 = off[n], s1 = off[n + 1];
        float m = -1e30f, l = 0.f, acc1 = 0.f, acc2 = 0.f;
        int j = s0;
        for (; j + 4 <= s1; j += 4) {
            unsigned int u0 = perm[j];
            unsigned int u1 = perm[j + 1];
            unsigned int u2 = perm[j + 2];
            unsigned int u3 = perm[j + 3];
            unsigned int g0 = xl32[(u0 & 0xffffu) * 64 + lane];
            unsigned int g1 = xl32[(u1 & 0xffffu) * 64 + lane];
            unsigned int g2 = xl32[(u2 & 0xffffu) * 64 + lane];
            unsigned int g3 = xl32[(u3 & 0xffffu) * 64 + lane];
            float e0 = bfhi(u0), e1 = bfhi(u1), e2 = bfhi(u2), e3 = bfhi(u3);
            float x01 = bflo(g0), x02 = bfhi(g0);
            float x11 = bflo(g1), x12 = bfhi(g1);
            float x21 = bflo(g2), x22 = bfhi(g2);
            float x31 = bflo(g3), x32 = bfhi(g3);
            float p0, p1, p2, p3;
            {
                float v1 = x01 + xr1 + e0 * we1, v2 = x02 + xr2 + e0 * we2;
                v1 = (v1 > 0.f) ? v1 : 0.2f * v1;
                v2 = (v2 > 0.f) ? v2 : 0.2f * v2;
                p0 = v1 * a1 + v2 * a2;
            }
            {
                float v1 = x11 + xr1 + e1 * we1, v2 = x12 + xr2 + e1 * we2;
                v1 = (v1 > 0.f) ? v1 : 0.2f * v1;
                v2 = (v2 > 0.f) ? v2 : 0.2f * v2;
                p1 = v1 * a1 + v2 * a2;
            }
            {
                float v1 = x21 + xr1 + e2 * we1, v2 = x22 + xr2 + e2 * we2;
                v1 = (v1 > 0.f) ? v1 : 0.2f * v1;
                v2 = (v2 > 0.f) ? v2 : 0.2f * v2;
                p2 = v1 * a1 + v2 * a2;
            }
            {
                float v1 = x31 + xr1 + e3 * we1, v2 = x32 + xr2 + e3 * we2;
                v1 = (v1 > 0.f) ? v1 : 0.2f * v1;
                v2 = (v2 > 0.f) ? v2 : 0.2f * v2;
                p3 = v1 * a1 + v2 * a2;
            }
            p0 += __shfl_xor(p0, 1, 64); p1 += __shfl_xor(p1, 1, 64);
            p2 += __shfl_xor(p2, 1, 64); p3 += __shfl_xor(p3, 1, 64);
            p0 += __shfl_xor(p0, 2, 64); p1 += __shfl_xor(p1, 2, 64);
            p2 += __shfl_xor(p2, 2, 64); p3 += __shfl_xor(p3, 2, 64);
            p0 += __shfl_xor(p0, 4, 64); p1 += __shfl_xor(p1, 4, 64);
            p2 += __shfl_xor(p2, 4, 64); p3 += __shfl_xor(p3, 4, 64);
            p0 += __shfl_xor(p0, 8, 64); p1 += __shfl_xor(p1, 8, 64);
            p2 += __shfl_xor(p2, 8, 64); p3 += __shfl_xor(p3, 8, 64);
            float nm = fmaxf(fmaxf(m, fmaxf(p0, p1)), fmaxf(p2, p3));
            float sc = __expf(m - nm);
            float E0 = __expf(p0 - nm);
            float E1 = __expf(p1 - nm);
            float E2 = __expf(p2 - nm);
            float E3 = __expf(p3 - nm);
            l = l * sc + E0 + E1 + E2 + E3;
            acc1 = acc1 * sc + E0 * x01 + E1 * x11 + E2 * x21 + E3 * x31;
            acc2 = acc2 * sc + E0 * x02 + E1 * x12 + E2 * x22 + E3 * x32;
            m = nm;
        }
        for (; j < s1; ++j) {
            unsigned int u0 = perm[j];
            unsigned int g0 = xl32[(u0 & 0xffffu) * 64 + lane];
            float e0 = bfhi(u0);
            float x01 = bflo(g0), x02 = bfhi(g0);
            float v1 = x01 + xr1 + e0 * we1, v2 = x02 + xr2 + e0 * we2;
            v1 = (v1 > 0.f) ? v1 : 0.2f * v1;
            v2 = (v2 > 0.f) ? v2 : 0.2f * v2;
            float p = v1 * a1 + v2 * a2;
            p += __shfl_xor(p, 1, 64);
            p += __shfl_xor(p, 2, 64);
            p += __shfl_xor(p, 4, 64);
            p += __shfl_xor(p, 8, 64);
            float nm = fmaxf(m, p);
            float sc = __expf(m - nm);
            float ee = __expf(p - nm);
            l = l * sc + ee;
            acc1 = acc1 * sc + ee * x01;
            acc2 = acc2 * sc + ee * x02;
            m = nm;
        }
        float inv = 1.f / fmaxf(l, 1e-30f);
        *(float2*)(outp + n * 128 + c) = make_float2(acc1 * inv, acc2 * inv);
    }
}

// ---------------------------------------------------------------------------
// k_epi v7: 512 threads / 8 waves (R13 structure) + hi/lo bf16 LDS pairs
// precomputed ONCE by producer phases (R8 numerics, correctness-passed).
// FFN A-fragments are direct ds_read_b128 with ZERO VALU — removes the
// 8x-redundant per-wave split8 work that R13's counters exposed
// (VALUBusy 31.5%). z (fp32) aliased over s_th after FFN2's barrier
// (exact size match: 32*264*2 = 32*132*4 = 16896 B).
// ---------------------------------------------------------------------------
__global__ __launch_bounds__(512) void k_epi(const float* out_agg, const float* x,
                                             const float* bias_out,
                                             const float* W_gate, const float* b_gate,
                                             const bf16* w1h, const bf16* w1l,
                                             const float* b_ffn1,
                                             const bf16* w2h, const bf16* w2l,
                                             const float* b_ffn2,
                                             const float* gamma, const float* beta,
                                             float* out) {
    __shared__ __align__(16) bf16 s_yh[32][136];   // h, then y (hi)
    __shared__ __align__(16) bf16 s_yl[32][136];   // h, then y (lo)
    __shared__ __align__(16) bf16 s_th[32][264];   // t hi; later fp32 z[32][132]
    __shared__ __align__(16) bf16 s_tl[32][264];   // t lo
    __shared__ float s_g[32];
    __shared__ float s_mu[32], s_rs[32];
    const int tid = threadIdx.x;
    const int lane = tid & 63;
    const int wvi  = tid >> 6;          // wave 0..7
    const int n0 = blockIdx.x * 32;
    int nn = NODES - n0; if (nn > 32) nn = 32;

    // phase 1: h = elu(out_agg + bias_out) -> hi/lo LDS (2 iters of float4)
    for (int it = 0; it < 2; ++it) {
        int idx4 = (it * 512 + tid) * 4;
        int n = idx4 >> 7, j = idx4 & 127;
        float4 w = make_float4(0.f, 0.f, 0.f, 0.f);
        if (n < nn) {
            float4 v  = *(const float4*)(out_agg + (n0 + n) * 128 + j);
            float4 bv = *(const float4*)(bias_out + j);
            float t0 = v.x + bv.x, t1 = v.y + bv.y;
            float t2 = v.z + bv.z, t3 = v.w + bv.w;
            w.x = (t0 > 0.f) ? t0 : (__expf(t0) - 1.f);
            w.y = (t1 > 0.f) ? t1 : (__expf(t1) - 1.f);
            w.z = (t2 > 0.f) ? t2 : (__expf(t2) - 1.f);
            w.w = (t3 > 0.f) ? t3 : (__expf(t3) - 1.f);
        }
        unsigned short hx, lx, hy, ly, hz, lz, hw, lw;
        hilo(w.x, hx, lx); hilo(w.y, hy, ly);
        hilo(w.z, hz, lz); hilo(w.w, hw, lw);
        uint2 uh = make_uint2((unsigned)hx | ((unsigned)hy << 16),
                              (unsigned)hz | ((unsigned)hw << 16));
        uint2 ul = make_uint2((unsigned)lx | ((unsigned)ly << 16),
                              (unsigned)lz | ((unsigned)lw << 16));
        *(uint2*)&s_yh[n][j] = uh;
        *(uint2*)&s_yl[n][j] = ul;
    }
    __syncthreads();
    // gate: 16 threads per node (512 threads, 32 nodes), h = hi + lo
    {
        int n = tid >> 4, kb = (tid & 15) * 8;
        float g = 0.f;
        #pragma unroll
        for (int k = 0; k < 8; k += 4) {
            uint2 uh = *(const uint2*)&s_yh[n][kb + k];
            uint2 ul = *(const uint2*)&s_yl[n][kb + k];
            float4 wg = *(const float4*)(W_gate + kb + k);
            g += (bflo(uh.x) + bflo(ul.x)) * wg.x;
            g += (bfhi(uh.x) + bfhi(ul.x)) * wg.y;
            g += (bflo(uh.y) + bflo(ul.y)) * wg.z;
            g += (bfhi(uh.y) + bfhi(ul.y)) * wg.w;
        }
        g += __shfl_xor(g, 1, 64);
        g += __shfl_xor(g, 2, 64);
        g += __shfl_xor(g, 4, 64);
        g += __shfl_xor(g, 8, 64);
        if ((tid & 15) == 0) s_g[n] = 1.f / (1.f + __expf(-(g + b_gate[0])));
    }
    __syncthreads();
    // y = g*h + (1-g)*x -> hi/lo back into same slots (thread-local slots)
    for (int it = 0; it < 2; ++it) {
        int idx4 = (it * 512 + tid) * 4;
        int n = idx4 >> 7, j = idx4 & 127;
        if (n < nn) {
            float g = s_g[n];
            float4 xv = *(const float4*)(x + (n0 + n) * 128 + j);
            uint2 uh = *(const uint2*)&s_yh[n][j];
            uint2 ul = *(const uint2*)&s_yl[n][j];
            float y0 = g * (bflo(uh.x) + bflo(ul.x)) + (1.f - g) * xv.x;
            float y1 = g * (bfhi(uh.x) + bfhi(ul.x)) + (1.f - g) * xv.y;
            float y2 = g * (bflo(uh.y) + bflo(ul.y)) + (1.f - g) * xv.z;
            float y3 = g * (bfhi(uh.y) + bfhi(ul.y)) + (1.f - g) * xv.w;
            unsigned short hx, lx, hy, ly, hz, lz, hw, lw;
            hilo(y0, hx, lx); hilo(y1, hy, ly);
            hilo(y2, hz, lz); hilo(y3, hw, lw);
            uint2 nh = make_uint2((unsigned)hx | ((unsigned)hy << 16),
                                  (unsigned)hz | ((unsigned)hw << 16));
            uint2 nl = make_uint2((unsigned)lx | ((unsigned)ly << 16),
                                  (unsigned)lz | ((unsigned)lw << 16));
            *(uint2*)&s_yh[n][j] = nh;
            *(uint2*)&s_yl[n][j] = nl;
        }
    }
    __syncthreads();

    const int wv   = wvi;
    const int ln   = lane;
    const int lrow = ln & 15;           // A row / B,D col within tile
    const int lk8  = (ln >> 4) << 3;    // k chunk base: 0,8,16,24

    // FFN1: t = relu(y @ W1 + b1). M=32 (2 tiles), per-wave N=32 (2 tiles), K=128.
    f32x4 acc1[2][2];
    #pragma unroll
    for (int mt = 0; mt < 2; ++mt)
        #pragma unroll
        for (int i = 0; i < 2; ++i)
            acc1[mt][i] = (f32x4){0.f, 0.f, 0.f, 0.f};
    #pragma unroll
    for (int kk = 0; kk < 4; ++kk) {
        int k0 = kk * 32 + lk8;
        bf16x8 a0h = *(const bf16x8*)&s_yh[lrow][k0];
        bf16x8 a0l = *(const bf16x8*)&s_yl[lrow][k0];
        bf16x8 a1h = *(const bf16x8*)&s_yh[16 + lrow][k0];
        bf16x8 a1l = *(const bf16x8*)&s_yl[16 + lrow][k0];
        #pragma unroll
        for (int i = 0; i < 2; ++i) {
            int col = (wv << 5) + (i << 4) + lrow;
            bf16x8 bh = *(const bf16x8*)(w1h + col * 128 + k0);
            bf16x8 bl = *(const bf16x8*)(w1l + col * 128 + k0);
            acc1[0][i] = __builtin_amdgcn_mfma_f32_16x16x32_bf16(a0l, bh, acc1[0][i], 0, 0, 0);
            acc1[0][i] = __builtin_amdgcn_mfma_f32_16x16x32_bf16(a0h, bl, acc1[0][i], 0, 0, 0);
            acc1[0][i] = __builtin_amdgcn_mfma_f32_16x16x32_bf16(a0h, bh, acc1[0][i], 0, 0, 0);
            acc1[1][i] = __builtin_amdgcn_mfma_f32_16x16x32_bf16(a1l, bh, acc1[1][i], 0, 0, 0);
            acc1[1][i] = __builtin_amdgcn_mfma_f32_16x16x32_bf16(a1h, bl, acc1[1][i], 0, 0, 0);
            acc1[1][i] = __builtin_amdgcn_mfma_f32_16x16x32_bf16(a1h, bh, acc1[1][i], 0, 0, 0);
        }
    }
    // epilogue: +b1, relu, split ONCE -> s_th/s_tl
    #pragma unroll
    for (int mt = 0; mt < 2; ++mt) {
        #pragma unroll
        for (int i = 0; i < 2; ++i) {
            int col = (wv << 5) + (i << 4) + lrow;
            float bv = b_ffn1[col];
            #pragma unroll
            for (int r = 0; r < 4; ++r) {
                int row = (mt << 4) + ((ln >> 4) << 2) + r;
                float v = fmaxf(acc1[mt][i][r] + bv, 0.f);
                unsigned short h, l;
                hilo(v, h, l);
                *(unsigned short*)&s_th[row][col] = h;
                *(unsigned short*)&s_tl[row][col] = l;
            }
        }
    }
    __syncthreads();

    // FFN2: ffn = t @ W2 + b2. M=32 (2 tiles), per-wave N=16 (1 tile), K=256.
    f32x4 acc2[2];
    acc2[0] = (f32x4){0.f, 0.f, 0.f, 0.f};
    acc2[1] = (f32x4){0.f, 0.f, 0.f, 0.f};
    #pragma unroll
    for (int kk = 0; kk < 8; ++kk) {
        int k0 = kk * 32 + lk8;
        bf16x8 a0h = *(const bf16x8*)&s_th[lrow][k0];
        bf16x8 a0l = *(const bf16x8*)&s_tl[lrow][k0];
        bf16x8 a1h = *(const bf16x8*)&s_th[16 + lrow][k0];
        bf16x8 a1l = *(const bf16x8*)&s_tl[16 + lrow][k0];
        int col = (wv << 4) + lrow;
        bf16x8 bh = *(const bf16x8*)(w2h + col * 256 + k0);
        bf16x8 bl = *(const bf16x8*)(w2l + col * 256 + k0);
        acc2[0] = __builtin_amdgcn_mfma_f32_16x16x32_bf16(a0l, bh, acc2[0], 0, 0, 0);
        acc2[0] = __builtin_amdgcn_mfma_f32_16x16x32_bf16(a0h, bl, acc2[0], 0, 0, 0);
        acc2[0] = __builtin_amdgcn_mfma_f32_16x16x32_bf16(a0h, bh, acc2[0], 0, 0, 0);
        acc2[1] = __builtin_amdgcn_mfma_f32_16x16x32_bf16(a1l, bh, acc2[1], 0, 0, 0);
        acc2[1] = __builtin_amdgcn_mfma_f32_16x16x32_bf16(a1h, bl, acc2[1], 0, 0, 0);
        acc2[1] = __builtin_amdgcn_mfma_f32_16x16x32_bf16(a1h, bh, acc2[1], 0, 0, 0);
    }
    __syncthreads();   // all FFN2 reads of s_th/s_tl complete before z reuse
    // epilogue: z = y + ffn + b2 -> fp32 into s_th region (z[32][132])
    float* s_z = (float*)&s_th[0][0];
    {
        int col = (wv << 4) + lrow;
        float bv = b_ffn2[col];
        #pragma unroll
        for (int mt = 0; mt < 2; ++mt) {
            #pragma unroll
            for (int r = 0; r < 4; ++r) {
                int row = (mt << 4) + ((ln >> 4) << 2) + r;
                float yv = __bfloat162float(s_yh[row][col]) +
                           __bfloat162float(s_yl[row][col]);
                s_z[row * 132 + col] = yv + acc2[mt][r] + bv;
            }
        }
    }
    __syncthreads();
    // LayerNorm stats: 16 threads per node
    {
        int n = tid >> 4, kb = (tid & 15) * 8;
        float4 v0 = *(const float4*)&s_z[n * 132 + kb];
        float4 v1 = *(const float4*)&s_z[n * 132 + kb + 4];
        float s  = v0.x + v0.y + v0.z + v0.w + v1.x + v1.y + v1.z + v1.w;
        float ss = v0.x * v0.x + v0.y * v0.y + v0.z * v0.z + v0.w * v0.w
                 + v1.x * v1.x + v1.y * v1.y + v1.z * v1.z + v1.w * v1.w;
        s  += __shfl_xor(s, 1, 64);  ss += __shfl_xor(ss, 1, 64);
        s  += __shfl_xor(s, 2, 64);  ss += __shfl_xor(ss, 2, 64);
        s  += __shfl_xor(s, 4, 64);  ss += __shfl_xor(ss, 4, 64);
        s  += __shfl_xor(s, 8, 64);  ss += __shfl_xor(ss, 8, 64);
        if ((tid & 15) == 0) {
            float mu = s * (1.f / 128.f);
            float var = ss * (1.f / 128.f) - mu * mu;
            s_mu[n] = mu;
            s_rs[n] = rsqrtf(fmaxf(var, 0.f) + 1e-5f);
        }
    }
    __syncthreads();
    // normalize + store (fp32): 4096 floats, 512 threads x float4 x 2 iters
    for (int it = 0; it < 2; ++it) {
        int idx4 = (it * 512 + tid) * 4;
        int n = idx4 >> 7, j = idx4 & 127;
        if (n < nn) {
            float mu = s_mu[n], rs = s_rs[n];
            float4 gv = *(const float4*)(gamma + j);
            float4 bv = *(const float4*)(beta + j);
            float4 v = *(const float4*)&s_z[n * 132 + j];
            float4 o;
            o.x = (v.x - mu) * rs * gv.x + bv.x;
            o.y = (v.y - mu) * rs * gv.y + bv.y;
            o.z = (v.z - mu) * rs * gv.z + bv.z;
            o.w = (v.w - mu) * rs * gv.w + bv.w;
            *(float4*)(out + (n0 + n) * 128 + j) = o;
        }
    }
}

// ---------------------------------------------------------------------------
extern "C" void kernel_launch(void* const* d_in, const int* in_sizes, int n_in,
                              void* d_out, int out_size, void* d_ws, size_t ws_size,
                              hipStream_t stream) {
    const float* x         = (const float*)d_in[0];
    const float* edge_attr = (const float*)d_in[1];
    const int* edge_index  = (const int*)d_in[17];
    float* out = (float*)d_out;

    char* base = (char*)d_ws;
    // workspace layout (29,600,064 B total, hardware-proven extents):
    float* sum_ea  = (float*)(base + 16);                     // 16 B
    int*   rhist   = (int*)  (base + 32);                     // 65536
    bf16*  w1t_hi  = (bf16*) (base + 32 + 65536);             // 65536 (disjoint from rhist)
    bf16*  w1t_lo  = (bf16*) (base + 32 + 131072);            // 65536 -> ends 196640 < 200032
    int*   off     = (int*)  (base + 200032);                 // 200004 (+pad)
    int*   base_r  = (int*)  (base + 400064);                 // 50 ints (pad to 256)
    bf16*  w2t_hi  = (bf16*) (base + 400064 + 256);           // 65536 (disjoint from base_r)
    bf16*  w2t_lo  = (bf16*) (base + 400064 + 256 + 65536);   // ends 531392 < 600064
    unsigned int* perm = (unsigned int*)(base + 600064);      // 3400000
    bf16*  xl      = (bf16*) (base + 4000064);                // 12800000
    bf16*  xr      = (bf16*) (base + 16800064);               // 12800000
    // xform weight split pairs: perm head +1024 (consumed by k_fuse, dead
    // before k_group writes perm). 4 x 32768 B.
    bf16*  wxlh    = (bf16*) (base + 600064 + 1024);
    bf16*  wxll    = (bf16*) (base + 600064 + 1024 + 32768);
    bf16*  wxrh    = (bf16*) (base + 600064 + 1024 + 65536);
    bf16*  wxrl    = (bf16*) (base + 600064 + 1024 + 98304);
    // range-partitioned (dst,payload) pairs: head of d_out (dead until k_agg).
    uint2* tmp2    = (uint2*)d_out;                           // 6.8 MB

    hipMemsetAsync(sum_ea, 0, 16, stream);

    const int NTILES = (NODES + 31) / 32;  // 1563

    k_wx      <<<384, 256, 0, stream>>>((const float*)d_in[2], (const float*)d_in[4],
                                        (const float*)d_in[11], (const float*)d_in[13],
                                        wxlh, wxll, wxrh, wxrl,
                                        w1t_hi, w1t_lo, w2t_hi, w2t_lo);
    k_fuse    <<<FUSE_GRID, 256, 0, stream>>>(edge_attr, edge_index, sum_ea, rhist,
                                              x, wxlh, wxll, wxrh, wxrl,
                                              (const float*)d_in[3], (const float*)d_in[5],
                                              xl, xr);
    k_rscan   <<<1, 256, 0, stream>>>(rhist, base_r, off);
    k_scatter <<<SB, 256, 0, stream>>>(edge_index, edge_attr, sum_ea, rhist, tmp2);
    k_group   <<<NRANGE, 1024, 0, stream>>>(tmp2, base_r, off, perm);
    k_agg     <<<3125, 256, 0, stream>>>((const unsigned int*)xl,
                                         (const unsigned int*)xr,
                                         perm, off,
                                         (const float*)d_in[6], (const float*)d_in[7],
                                         out);
    k_epi     <<<NTILES, 512, 0, stream>>>(out, x, (const float*)d_in[8],
                                           (const float*)d_in[9], (const float*)d_in[10],
                                           w1t_hi, w1t_lo, (const float*)d_in[12],
                                           w2t_hi, w2t_lo, (const float*)d_in[14],
                                           (const float*)d_in[15], (const float*)d_in[16],
                                           out);
}